// Round 1
// baseline (4425.486 us; speedup 1.0000x reference)
//
#include <hip/hip_runtime.h>
#include <cstdint>
#include <cstddef>

#define NN 20000
#define NE 640000

typedef __attribute__((ext_vector_type(8))) short short8;
typedef __attribute__((ext_vector_type(4))) short short4v;
typedef __attribute__((ext_vector_type(4))) float floatx4;

__device__ __forceinline__ unsigned short f2bf(float f) {
  union { float f; unsigned int u; } v; v.f = f;
  return (unsigned short)((v.u + 0x7FFFu + ((v.u >> 16) & 1u)) >> 16);
}
__device__ __forceinline__ float bf2f(unsigned short s) {
  union { unsigned int u; float f; } v; v.u = ((unsigned int)s) << 16;
  return v.f;
}
__device__ __forceinline__ float silu_f(float v) {
  return v / (1.0f + __expf(-v));
}

// packed-A LDS layout: element (k, m) of a [64 x K] tile lives at
// ((k/8)*64 + m)*8 + (k%8)  -> a lane's 8 consecutive k are 16B contiguous.
#define AIDX(k, m) (((((k) >> 3) * 64 + (m)) << 3) + ((k) & 7))

// One 64xK @ Kx128 layer for this wave: 4 M-tiles x 2 N-tiles (n0, n0+16).
template<int KT>
__device__ __forceinline__ void gemm_tile(const unsigned short* Alds,
                                          const unsigned short* __restrict__ Wpk,
                                          floatx4 acc[4][2],
                                          int quad, int l16, int n0)
{
#pragma unroll
  for (int mt = 0; mt < 4; ++mt) {
    acc[mt][0] = (floatx4)0.0f;
    acc[mt][1] = (floatx4)0.0f;
  }
#pragma unroll
  for (int kt = 0; kt < KT; ++kt) {
    const int kb = kt * 4 + quad;
    short8 b0 = *(const short8*)&Wpk[(kb * 128 + n0 + l16) * 8];
    short8 b1 = *(const short8*)&Wpk[(kb * 128 + n0 + 16 + l16) * 8];
#pragma unroll
    for (int mt = 0; mt < 4; ++mt) {
      short8 a = *(const short8*)&Alds[(kb * 64 + mt * 16 + l16) * 8];
      acc[mt][0] = __builtin_amdgcn_mfma_f32_16x16x32_bf16(a, b0, acc[mt][0], 0, 0, 0);
      acc[mt][1] = __builtin_amdgcn_mfma_f32_16x16x32_bf16(a, b1, acc[mt][1], 0, 0, 0);
    }
  }
}

// Pack fp32 weight [K,128] -> bf16 [K/8][128][8]
__global__ void pack_weights(const float* __restrict__ src,
                             unsigned short* __restrict__ dst, int total) {
  int idx = blockIdx.x * blockDim.x + threadIdx.x;
  if (idx >= total) return;
  int k = idx >> 7, n = idx & 127;
  dst[(((k >> 3) * 128 + n) << 3) + (k & 7)] = f2bf(src[idx]);
}

__global__ __launch_bounds__(256) void edge_kernel(
    const float* __restrict__ h, const float* __restrict__ x,
    const int* __restrict__ ei,
    const unsigned short* __restrict__ ew1pk, const float* __restrict__ ew1full,
    const float* __restrict__ eb1,
    const unsigned short* __restrict__ ew2pk, const float* __restrict__ eb2,
    const unsigned short* __restrict__ cw1pk, const float* __restrict__ cb1,
    const float* __restrict__ cw2,
    float* __restrict__ m_i, float* __restrict__ x_acc)
{
  __shared__ __align__(16) unsigned short A1[16384]; // 32KB: layer1 A; lower half reused as A2, upper as A4
  __shared__ __align__(16) unsigned short A3[8192];  // 16KB: m_ij (bf16)
  __shared__ float s_cd[64][3];
  __shared__ float s_rad[64];
  __shared__ int   s_row[64];
  __shared__ float s_cw2[128];

  const int tid  = threadIdx.x;
  const int wave = tid >> 6;
  const int lane = tid & 63;
  const int quad = lane >> 4;
  const int l16  = lane & 15;
  const int blk  = blockIdx.x;
  const int n0   = wave * 32;

  if (tid < 128) s_cw2[tid] = cw2[tid];

  // edge_index may be int64 (viewed as int32 pairs) or int32; detect.
  const bool is64 = ((ei[1] | ei[3] | ei[5] | ei[7] | ei[9] | ei[11]) == 0);

  // ---- gather stage: 4 threads per edge
  {
    const int e = tid >> 2;
    const int p = tid & 3;
    const int ge = blk * 64 + e;
    int r, c;
    if (is64) { r = ei[2 * ge]; c = ei[2 * (NE + ge)]; }
    else      { r = ei[ge];     c = ei[NE + ge]; }
    if (p == 0) {
      float dx = x[r * 3 + 0] - x[c * 3 + 0];
      float dy = x[r * 3 + 1] - x[c * 3 + 1];
      float dz = x[r * 3 + 2] - x[c * 3 + 2];
      s_cd[e][0] = dx; s_cd[e][1] = dy; s_cd[e][2] = dz;
      s_rad[e] = dx * dx + dy * dy + dz * dz;
      s_row[e] = r;
    }
    const float* hr = h + (size_t)r * 128 + p * 32;
    const float* hc = h + (size_t)c * 128 + p * 32;
#pragma unroll
    for (int i = 0; i < 8; ++i) {
      float4 v = *(const float4*)(hr + i * 4);
      int k = p * 32 + i * 4;
      short4v w;
      w[0] = (short)f2bf(v.x); w[1] = (short)f2bf(v.y);
      w[2] = (short)f2bf(v.z); w[3] = (short)f2bf(v.w);
      *(short4v*)&A1[AIDX(k, e)] = w;
      float4 u = *(const float4*)(hc + i * 4);
      int k2 = 128 + k;
      short4v w2;
      w2[0] = (short)f2bf(u.x); w2[1] = (short)f2bf(u.y);
      w2[2] = (short)f2bf(u.z); w2[3] = (short)f2bf(u.w);
      *(short4v*)&A1[AIDX(k2, e)] = w2;
    }
  }
  __syncthreads();

  // ---- layer 1: [64,256] @ ew1 (+ radial column + bias), silu
  floatx4 acc1[4][2];
  gemm_tile<8>(A1, ew1pk, acc1, quad, l16, n0);
  {
    const float b0 = eb1[n0 + l16],            b1 = eb1[n0 + 16 + l16];
    const float w0 = ew1full[256 * 128 + n0 + l16];
    const float w1 = ew1full[256 * 128 + n0 + 16 + l16];
    __syncthreads();  // everyone done reading A1 before overwriting lower half
#pragma unroll
    for (int mt = 0; mt < 4; ++mt) {
#pragma unroll
      for (int r = 0; r < 4; ++r) {
        const int m = mt * 16 + quad * 4 + r;
        const float rv = s_rad[m];
        const float v0 = acc1[mt][0][r] + b0 + rv * w0;
        const float v1 = acc1[mt][1][r] + b1 + rv * w1;
        const int k0 = n0 + l16, k1 = n0 + 16 + l16;
        A1[AIDX(k0, m)] = f2bf(silu_f(v0));
        A1[AIDX(k1, m)] = f2bf(silu_f(v1));
      }
    }
  }
  __syncthreads();

  // ---- layer 2: [64,128] @ ew2 + bias, silu -> m_ij into A3
  floatx4 acc2[4][2];
  gemm_tile<4>(A1, ew2pk, acc2, quad, l16, n0);
  {
    const float b0 = eb2[n0 + l16], b1 = eb2[n0 + 16 + l16];
#pragma unroll
    for (int mt = 0; mt < 4; ++mt) {
#pragma unroll
      for (int r = 0; r < 4; ++r) {
        const int m = mt * 16 + quad * 4 + r;
        const int k0 = n0 + l16, k1 = n0 + 16 + l16;
        A3[AIDX(k0, m)] = f2bf(silu_f(acc2[mt][0][r] + b0));
        A3[AIDX(k1, m)] = f2bf(silu_f(acc2[mt][1][r] + b1));
      }
    }
  }
  __syncthreads();

  // ---- coord layer: silu(m_ij @ cw1 + cb1) into A4 (= A1 upper half)
  floatx4 acc3[4][2];
  gemm_tile<4>(A3, cw1pk, acc3, quad, l16, n0);
  unsigned short* A4 = A1 + 8192;
  {
    const float b0 = cb1[n0 + l16], b1 = cb1[n0 + 16 + l16];
#pragma unroll
    for (int mt = 0; mt < 4; ++mt) {
#pragma unroll
      for (int r = 0; r < 4; ++r) {
        const int m = mt * 16 + quad * 4 + r;
        const int k0 = n0 + l16, k1 = n0 + 16 + l16;
        A4[AIDX(k0, m)] = f2bf(silu_f(acc3[mt][0][r] + b0));
        A4[AIDX(k1, m)] = f2bf(silu_f(acc3[mt][1][r] + b1));
      }
    }
  }
  __syncthreads();

  // ---- coord_weight dot + atomics
  {
    const int e = tid >> 2, p = tid & 3;
    float dot = 0.0f;
#pragma unroll
    for (int cb = 0; cb < 4; ++cb) {
      const int kb = p * 4 + cb;
      short8 v = *(const short8*)&A4[(kb * 64 + e) * 8];
#pragma unroll
      for (int j = 0; j < 8; ++j)
        dot += bf2f((unsigned short)v[j]) * s_cw2[kb * 8 + j];
    }
    dot += __shfl_xor(dot, 1);
    dot += __shfl_xor(dot, 2);
    const int r = s_row[e];
    if (p < 3) atomicAdd(&x_acc[r * 3 + p], s_cd[e][p] * dot);
#pragma unroll
    for (int cb = 0; cb < 4; ++cb) {
      const int kb = p * 4 + cb;
      short8 v = *(const short8*)&A3[(kb * 64 + e) * 8];
#pragma unroll
      for (int j = 0; j < 8; ++j)
        atomicAdd(&m_i[r * 128 + kb * 8 + j], bf2f((unsigned short)v[j]));
    }
  }
}

__global__ __launch_bounds__(256) void node_kernel(
    const float* __restrict__ h, const float* __restrict__ m_i,
    const unsigned short* __restrict__ nw1pk, const float* __restrict__ nb1,
    const unsigned short* __restrict__ nw2pk, const float* __restrict__ nb2,
    float* __restrict__ out_h)
{
  __shared__ __align__(16) unsigned short A1[16384]; // 32KB; lower half reused as A2

  const int tid  = threadIdx.x;
  const int wave = tid >> 6;
  const int lane = tid & 63;
  const int quad = lane >> 4;
  const int l16  = lane & 15;
  const int blk  = blockIdx.x;
  const int n0   = wave * 32;

  // stage [h | m_i] rows blk*64..blk*64+63 as bf16 packed-A
  {
    const int e = tid >> 2, p = tid & 3;
    const int row = blk * 64 + e;
    const int rc = row < NN ? row : NN - 1;
    const float* hr = h   + (size_t)rc * 128 + p * 32;
    const float* mr = m_i + (size_t)rc * 128 + p * 32;
#pragma unroll
    for (int i = 0; i < 8; ++i) {
      float4 v = *(const float4*)(hr + i * 4);
      int k = p * 32 + i * 4;
      short4v w;
      w[0] = (short)f2bf(v.x); w[1] = (short)f2bf(v.y);
      w[2] = (short)f2bf(v.z); w[3] = (short)f2bf(v.w);
      *(short4v*)&A1[AIDX(k, e)] = w;
      float4 u = *(const float4*)(mr + i * 4);
      int k2 = 128 + k;
      short4v w2;
      w2[0] = (short)f2bf(u.x); w2[1] = (short)f2bf(u.y);
      w2[2] = (short)f2bf(u.z); w2[3] = (short)f2bf(u.w);
      *(short4v*)&A1[AIDX(k2, e)] = w2;
    }
  }
  __syncthreads();

  floatx4 acc1[4][2];
  gemm_tile<8>(A1, nw1pk, acc1, quad, l16, n0);
  {
    const float b0 = nb1[n0 + l16], b1 = nb1[n0 + 16 + l16];
    __syncthreads();
#pragma unroll
    for (int mt = 0; mt < 4; ++mt) {
#pragma unroll
      for (int r = 0; r < 4; ++r) {
        const int m = mt * 16 + quad * 4 + r;
        const int k0 = n0 + l16, k1 = n0 + 16 + l16;
        A1[AIDX(k0, m)] = f2bf(silu_f(acc1[mt][0][r] + b0));
        A1[AIDX(k1, m)] = f2bf(silu_f(acc1[mt][1][r] + b1));
      }
    }
  }
  __syncthreads();

  floatx4 acc2[4][2];
  gemm_tile<4>(A1, nw2pk, acc2, quad, l16, n0);
  {
    const float b0 = nb2[n0 + l16], b1 = nb2[n0 + 16 + l16];
#pragma unroll
    for (int mt = 0; mt < 4; ++mt) {
#pragma unroll
      for (int r = 0; r < 4; ++r) {
        const int m = blk * 64 + mt * 16 + quad * 4 + r;
        if (m < NN) {
          const size_t base = (size_t)m * 128;
          const int c0 = n0 + l16, c1 = n0 + 16 + l16;
          out_h[base + c0] = h[base + c0] + acc2[mt][0][r] + b0;
          out_h[base + c1] = h[base + c1] + acc2[mt][1][r] + b1;
        }
      }
    }
  }
}

__global__ void x_kernel(const float* __restrict__ x,
                         const float* __restrict__ x_acc,
                         float* __restrict__ out_x) {
  int i = blockIdx.x * blockDim.x + threadIdx.x;
  if (i < NN * 3) out_x[i] = x[i] + x_acc[i] * (1.0f / 19999.0f);
}

extern "C" void kernel_launch(void* const* d_in, const int* in_sizes, int n_in,
                              void* d_out, int out_size, void* d_ws, size_t ws_size,
                              hipStream_t stream)
{
  const float* h   = (const float*)d_in[0];
  const float* x   = (const float*)d_in[1];
  const int*   ei  = (const int*)d_in[2];
  const float* ew1 = (const float*)d_in[3];
  const float* eb1 = (const float*)d_in[4];
  const float* ew2 = (const float*)d_in[5];
  const float* eb2 = (const float*)d_in[6];
  const float* nw1 = (const float*)d_in[7];
  const float* nb1 = (const float*)d_in[8];
  const float* nw2 = (const float*)d_in[9];
  const float* nb2 = (const float*)d_in[10];
  const float* cw1 = (const float*)d_in[11];
  const float* cb1 = (const float*)d_in[12];
  const float* cw2 = (const float*)d_in[13];

  char* ws = (char*)d_ws;
  float* m_i   = (float*)(ws);                 // 20000*128*4 = 10,240,000 B
  float* x_acc = (float*)(ws + 10240000);      // 20000*3*4  =    240,000 B
  constexpr size_t OFF_EW1 = 10480128;
  unsigned short* ew1pk = (unsigned short*)(ws + OFF_EW1);            // 65,536 B
  unsigned short* ew2pk = (unsigned short*)(ws + OFF_EW1 + 65536);    // 32,768 B
  unsigned short* cw1pk = (unsigned short*)(ws + OFF_EW1 + 98304);    // 32,768 B
  unsigned short* nw1pk = (unsigned short*)(ws + OFF_EW1 + 131072);   // 65,536 B
  unsigned short* nw2pk = (unsigned short*)(ws + OFF_EW1 + 196608);   // 32,768 B

  hipMemsetAsync(d_ws, 0, 10480000, stream);

  pack_weights<<<128, 256, 0, stream>>>(ew1, ew1pk, 256 * 128); // rows 0..255; row 256 read fp32
  pack_weights<<<64,  256, 0, stream>>>(ew2, ew2pk, 128 * 128);
  pack_weights<<<64,  256, 0, stream>>>(cw1, cw1pk, 128 * 128);
  pack_weights<<<128, 256, 0, stream>>>(nw1, nw1pk, 256 * 128);
  pack_weights<<<64,  256, 0, stream>>>(nw2, nw2pk, 128 * 128);

  edge_kernel<<<NE / 64, 256, 0, stream>>>(h, x, ei, ew1pk, ew1, eb1,
                                           ew2pk, eb2, cw1pk, cb1, cw2,
                                           m_i, x_acc);
  node_kernel<<<(NN + 63) / 64, 256, 0, stream>>>(h, m_i, nw1pk, nb1,
                                                  nw2pk, nb2, (float*)d_out);
  x_kernel<<<(NN * 3 + 255) / 256, 256, 0, stream>>>(x, x_acc,
                                                     (float*)d_out + (size_t)NN * 128);
}

// Round 2
// 611.039 us; speedup vs baseline: 7.2426x; 7.2426x over previous
//
#include <hip/hip_runtime.h>
#include <cstdint>
#include <cstddef>

#define NN 20000
#define NE 640000

typedef __attribute__((ext_vector_type(8))) short short8;
typedef __attribute__((ext_vector_type(4))) short short4v;
typedef __attribute__((ext_vector_type(4))) float floatx4;

__device__ __forceinline__ unsigned short f2bf(float f) {
  union { float f; unsigned int u; } v; v.f = f;
  return (unsigned short)((v.u + 0x7FFFu + ((v.u >> 16) & 1u)) >> 16);
}
__device__ __forceinline__ float bf2f(unsigned short s) {
  union { unsigned int u; float f; } v; v.u = ((unsigned int)s) << 16;
  return v.f;
}
__device__ __forceinline__ float silu_f(float v) {
  return v / (1.0f + __expf(-v));
}

__device__ __forceinline__ bool idx_is64(const int* ei) {
  return ((ei[1] | ei[3] | ei[5] | ei[7] | ei[9] | ei[11]) == 0);
}

// packed-A LDS layout: element (k, m) of a [64 x K] tile lives at
// ((k/8)*64 + m)*8 + (k%8)  -> a lane's 8 consecutive k are 16B contiguous.
#define AIDX(k, m) (((((k) >> 3) * 64 + (m)) << 3) + ((k) & 7))

// One 64xK @ Kx128 layer for this wave: 4 M-tiles x 2 N-tiles (n0, n0+16).
template<int KT>
__device__ __forceinline__ void gemm_tile(const unsigned short* Alds,
                                          const unsigned short* __restrict__ Wpk,
                                          floatx4 acc[4][2],
                                          int quad, int l16, int n0)
{
#pragma unroll
  for (int mt = 0; mt < 4; ++mt) {
    acc[mt][0] = (floatx4)0.0f;
    acc[mt][1] = (floatx4)0.0f;
  }
#pragma unroll
  for (int kt = 0; kt < KT; ++kt) {
    const int kb = kt * 4 + quad;
    short8 b0 = *(const short8*)&Wpk[(kb * 128 + n0 + l16) * 8];
    short8 b1 = *(const short8*)&Wpk[(kb * 128 + n0 + 16 + l16) * 8];
#pragma unroll
    for (int mt = 0; mt < 4; ++mt) {
      short8 a = *(const short8*)&Alds[(kb * 64 + mt * 16 + l16) * 8];
      acc[mt][0] = __builtin_amdgcn_mfma_f32_16x16x32_bf16(a, b0, acc[mt][0], 0, 0, 0);
      acc[mt][1] = __builtin_amdgcn_mfma_f32_16x16x32_bf16(a, b1, acc[mt][1], 0, 0, 0);
    }
  }
}

// Pack fp32 weight [K,128] -> bf16 [K/8][128][8]
__global__ void pack_weights(const float* __restrict__ src,
                             unsigned short* __restrict__ dst, int total) {
  int idx = blockIdx.x * blockDim.x + threadIdx.x;
  if (idx >= total) return;
  int k = idx >> 7, n = idx & 127;
  dst[(((k >> 3) * 128 + n) << 3) + (k & 7)] = f2bf(src[idx]);
}

// ---- CSR build ----
__global__ void hist_kernel(const int* __restrict__ ei, int* __restrict__ counts) {
  int e = blockIdx.x * blockDim.x + threadIdx.x;
  if (e >= NE) return;
  const bool is64 = idx_is64(ei);
  int r = is64 ? ei[2 * e] : ei[e];
  atomicAdd(&counts[r], 1);
}

__global__ void scan_kernel(const int* __restrict__ counts,
                            int* __restrict__ starts, int* __restrict__ cursor) {
  // single wave of 64 lanes
  const int lane = threadIdx.x;
  int carry = 0;
  for (int base = 0; base < NN; base += 64) {
    const int idx = base + lane;
    int v = (idx < NN) ? counts[idx] : 0;
    int s = v;
#pragma unroll
    for (int d = 1; d < 64; d <<= 1) {
      int t = __shfl_up(s, d);
      if (lane >= d) s += t;
    }
    const int excl = s - v + carry;
    if (idx < NN) { starts[idx] = excl; cursor[idx] = excl; }
    carry += __shfl(s, 63);
  }
  if (lane == 0) starts[NN] = carry;
}

__global__ void scatter_kernel(const int* __restrict__ ei,
                               int* __restrict__ cursor,
                               int* __restrict__ edge_order) {
  int e = blockIdx.x * blockDim.x + threadIdx.x;
  if (e >= NE) return;
  const bool is64 = idx_is64(ei);
  int r = is64 ? ei[2 * e] : ei[e];
  int pos = atomicAdd(&cursor[r], 1);
  edge_order[pos] = e;
}

// ---- edge MLP over sorted edges; plain coalesced stores, no atomics ----
__global__ __launch_bounds__(256) void edge_kernel(
    const float* __restrict__ h, const float* __restrict__ x,
    const int* __restrict__ ei, const int* __restrict__ edge_order,
    const unsigned short* __restrict__ ew1pk, const float* __restrict__ ew1full,
    const float* __restrict__ eb1,
    const unsigned short* __restrict__ ew2pk, const float* __restrict__ eb2,
    const unsigned short* __restrict__ cw1pk, const float* __restrict__ cb1,
    const float* __restrict__ cw2,
    unsigned short* __restrict__ m_sorted, float* __restrict__ xw)
{
  __shared__ __align__(16) unsigned short A1[16384]; // 32KB; lower half reused as A2, upper as A4
  __shared__ __align__(16) unsigned short A3[8192];  // 16KB: m_ij (bf16)
  __shared__ float s_cd[64][3];
  __shared__ float s_rad[64];
  __shared__ float s_cw2[128];

  const int tid  = threadIdx.x;
  const int wave = tid >> 6;
  const int lane = tid & 63;
  const int quad = lane >> 4;
  const int l16  = lane & 15;
  const int blk  = blockIdx.x;
  const int n0   = wave * 32;

  if (tid < 128) s_cw2[tid] = cw2[tid];

  const bool is64 = idx_is64(ei);

  // ---- gather stage: 4 threads per edge (sorted order)
  {
    const int e = tid >> 2;
    const int p = tid & 3;
    const int ge = edge_order[blk * 64 + e];
    int r, c;
    if (is64) { r = ei[2 * ge]; c = ei[2 * (NE + ge)]; }
    else      { r = ei[ge];     c = ei[NE + ge]; }
    if (p == 0) {
      float dx = x[r * 3 + 0] - x[c * 3 + 0];
      float dy = x[r * 3 + 1] - x[c * 3 + 1];
      float dz = x[r * 3 + 2] - x[c * 3 + 2];
      s_cd[e][0] = dx; s_cd[e][1] = dy; s_cd[e][2] = dz;
      s_rad[e] = dx * dx + dy * dy + dz * dz;
    }
    const float* hr = h + (size_t)r * 128 + p * 32;
    const float* hc = h + (size_t)c * 128 + p * 32;
#pragma unroll
    for (int i = 0; i < 8; ++i) {
      float4 v = *(const float4*)(hr + i * 4);
      int k = p * 32 + i * 4;
      short4v w;
      w[0] = (short)f2bf(v.x); w[1] = (short)f2bf(v.y);
      w[2] = (short)f2bf(v.z); w[3] = (short)f2bf(v.w);
      *(short4v*)&A1[AIDX(k, e)] = w;
      float4 u = *(const float4*)(hc + i * 4);
      int k2 = 128 + k;
      short4v w2;
      w2[0] = (short)f2bf(u.x); w2[1] = (short)f2bf(u.y);
      w2[2] = (short)f2bf(u.z); w2[3] = (short)f2bf(u.w);
      *(short4v*)&A1[AIDX(k2, e)] = w2;
    }
  }
  __syncthreads();

  // ---- layer 1: [64,256] @ ew1 (+ radial column + bias), silu
  floatx4 acc1[4][2];
  gemm_tile<8>(A1, ew1pk, acc1, quad, l16, n0);
  {
    const float b0 = eb1[n0 + l16],            b1 = eb1[n0 + 16 + l16];
    const float w0 = ew1full[256 * 128 + n0 + l16];
    const float w1 = ew1full[256 * 128 + n0 + 16 + l16];
    __syncthreads();  // everyone done reading A1 before overwriting lower half
#pragma unroll
    for (int mt = 0; mt < 4; ++mt) {
#pragma unroll
      for (int r = 0; r < 4; ++r) {
        const int m = mt * 16 + quad * 4 + r;
        const float rv = s_rad[m];
        const float v0 = acc1[mt][0][r] + b0 + rv * w0;
        const float v1 = acc1[mt][1][r] + b1 + rv * w1;
        const int k0 = n0 + l16, k1 = n0 + 16 + l16;
        A1[AIDX(k0, m)] = f2bf(silu_f(v0));
        A1[AIDX(k1, m)] = f2bf(silu_f(v1));
      }
    }
  }
  __syncthreads();

  // ---- layer 2: [64,128] @ ew2 + bias, silu -> m_ij into A3
  floatx4 acc2[4][2];
  gemm_tile<4>(A1, ew2pk, acc2, quad, l16, n0);
  {
    const float b0 = eb2[n0 + l16], b1 = eb2[n0 + 16 + l16];
#pragma unroll
    for (int mt = 0; mt < 4; ++mt) {
#pragma unroll
      for (int r = 0; r < 4; ++r) {
        const int m = mt * 16 + quad * 4 + r;
        const int k0 = n0 + l16, k1 = n0 + 16 + l16;
        A3[AIDX(k0, m)] = f2bf(silu_f(acc2[mt][0][r] + b0));
        A3[AIDX(k1, m)] = f2bf(silu_f(acc2[mt][1][r] + b1));
      }
    }
  }
  __syncthreads();

  // ---- coord layer: silu(m_ij @ cw1 + cb1) into A4 (= A1 upper half)
  floatx4 acc3[4][2];
  gemm_tile<4>(A3, cw1pk, acc3, quad, l16, n0);
  unsigned short* A4 = A1 + 8192;
  {
    const float b0 = cb1[n0 + l16], b1 = cb1[n0 + 16 + l16];
#pragma unroll
    for (int mt = 0; mt < 4; ++mt) {
#pragma unroll
      for (int r = 0; r < 4; ++r) {
        const int m = mt * 16 + quad * 4 + r;
        const int k0 = n0 + l16, k1 = n0 + 16 + l16;
        A4[AIDX(k0, m)] = f2bf(silu_f(acc3[mt][0][r] + b0));
        A4[AIDX(k1, m)] = f2bf(silu_f(acc3[mt][1][r] + b1));
      }
    }
  }
  __syncthreads();

  // ---- coord_weight dot + coalesced stores
  {
    const int e = tid >> 2, p = tid & 3;
    float dot = 0.0f;
#pragma unroll
    for (int cb = 0; cb < 4; ++cb) {
      const int kb = p * 4 + cb;
      short8 v = *(const short8*)&A4[(kb * 64 + e) * 8];
#pragma unroll
      for (int j = 0; j < 8; ++j)
        dot += bf2f((unsigned short)v[j]) * s_cw2[kb * 8 + j];
    }
    dot += __shfl_xor(dot, 1);
    dot += __shfl_xor(dot, 2);
    const size_t sp = (size_t)blk * 64 + e;
    if (p < 3) xw[sp * 4 + p] = s_cd[e][p] * dot;
#pragma unroll
    for (int cb = 0; cb < 4; ++cb) {
      const int kb = p * 4 + cb;
      short8 v = *(const short8*)&A3[(kb * 64 + e) * 8];
      *(short8*)&m_sorted[sp * 128 + kb * 8] = v;
    }
  }
}

// ---- per-node segment reduce: m_i fp32 + final x output ----
__global__ __launch_bounds__(256) void node_reduce_kernel(
    const unsigned short* __restrict__ m_sorted,
    const float* __restrict__ xw,
    const int* __restrict__ starts,
    const float* __restrict__ x,
    float* __restrict__ m_i, float* __restrict__ out_x)
{
  const int wave = threadIdx.x >> 6, lane = threadIdx.x & 63;
  const int node = blockIdx.x * 4 + wave;
  if (node >= NN) return;
  const int s = starts[node], e = starts[node + 1];
  float a0 = 0.f, a1 = 0.f, b0 = 0.f, b1 = 0.f, xa = 0.f, xb = 0.f;
  int r = s;
  for (; r + 1 < e; r += 2) {
    unsigned int v0 = *(const unsigned int*)(m_sorted + (size_t)r * 128 + lane * 2);
    unsigned int v1 = *(const unsigned int*)(m_sorted + (size_t)(r + 1) * 128 + lane * 2);
    a0 += bf2f((unsigned short)(v0 & 0xFFFF));
    a1 += bf2f((unsigned short)(v0 >> 16));
    b0 += bf2f((unsigned short)(v1 & 0xFFFF));
    b1 += bf2f((unsigned short)(v1 >> 16));
    if (lane < 3) {
      xa += xw[(size_t)r * 4 + lane];
      xb += xw[(size_t)(r + 1) * 4 + lane];
    }
  }
  if (r < e) {
    unsigned int v0 = *(const unsigned int*)(m_sorted + (size_t)r * 128 + lane * 2);
    a0 += bf2f((unsigned short)(v0 & 0xFFFF));
    a1 += bf2f((unsigned short)(v0 >> 16));
    if (lane < 3) xa += xw[(size_t)r * 4 + lane];
  }
  m_i[(size_t)node * 128 + lane * 2]     = a0 + b0;
  m_i[(size_t)node * 128 + lane * 2 + 1] = a1 + b1;
  if (lane < 3)
    out_x[node * 3 + lane] = x[node * 3 + lane] + (xa + xb) * (1.0f / (float)(NN - 1));
}

__global__ __launch_bounds__(256) void node_kernel(
    const float* __restrict__ h, const float* __restrict__ m_i,
    const unsigned short* __restrict__ nw1pk, const float* __restrict__ nb1,
    const unsigned short* __restrict__ nw2pk, const float* __restrict__ nb2,
    float* __restrict__ out_h)
{
  __shared__ __align__(16) unsigned short A1[16384]; // 32KB; lower half reused as A2

  const int tid  = threadIdx.x;
  const int wave = tid >> 6;
  const int lane = tid & 63;
  const int quad = lane >> 4;
  const int l16  = lane & 15;
  const int blk  = blockIdx.x;
  const int n0   = wave * 32;

  {
    const int e = tid >> 2, p = tid & 3;
    const int row = blk * 64 + e;
    const int rc = row < NN ? row : NN - 1;
    const float* hr = h   + (size_t)rc * 128 + p * 32;
    const float* mr = m_i + (size_t)rc * 128 + p * 32;
#pragma unroll
    for (int i = 0; i < 8; ++i) {
      float4 v = *(const float4*)(hr + i * 4);
      int k = p * 32 + i * 4;
      short4v w;
      w[0] = (short)f2bf(v.x); w[1] = (short)f2bf(v.y);
      w[2] = (short)f2bf(v.z); w[3] = (short)f2bf(v.w);
      *(short4v*)&A1[AIDX(k, e)] = w;
      float4 u = *(const float4*)(mr + i * 4);
      int k2 = 128 + k;
      short4v w2;
      w2[0] = (short)f2bf(u.x); w2[1] = (short)f2bf(u.y);
      w2[2] = (short)f2bf(u.z); w2[3] = (short)f2bf(u.w);
      *(short4v*)&A1[AIDX(k2, e)] = w2;
    }
  }
  __syncthreads();

  floatx4 acc1[4][2];
  gemm_tile<8>(A1, nw1pk, acc1, quad, l16, n0);
  {
    const float b0 = nb1[n0 + l16], b1 = nb1[n0 + 16 + l16];
    __syncthreads();
#pragma unroll
    for (int mt = 0; mt < 4; ++mt) {
#pragma unroll
      for (int r = 0; r < 4; ++r) {
        const int m = mt * 16 + quad * 4 + r;
        const int k0 = n0 + l16, k1 = n0 + 16 + l16;
        A1[AIDX(k0, m)] = f2bf(silu_f(acc1[mt][0][r] + b0));
        A1[AIDX(k1, m)] = f2bf(silu_f(acc1[mt][1][r] + b1));
      }
    }
  }
  __syncthreads();

  floatx4 acc2[4][2];
  gemm_tile<4>(A1, nw2pk, acc2, quad, l16, n0);
  {
    const float b0 = nb2[n0 + l16], b1 = nb2[n0 + 16 + l16];
#pragma unroll
    for (int mt = 0; mt < 4; ++mt) {
#pragma unroll
      for (int r = 0; r < 4; ++r) {
        const int m = blk * 64 + mt * 16 + quad * 4 + r;
        if (m < NN) {
          const size_t base = (size_t)m * 128;
          const int c0 = n0 + l16, c1 = n0 + 16 + l16;
          out_h[base + c0] = h[base + c0] + acc2[mt][0][r] + b0;
          out_h[base + c1] = h[base + c1] + acc2[mt][1][r] + b1;
        }
      }
    }
  }
}

extern "C" void kernel_launch(void* const* d_in, const int* in_sizes, int n_in,
                              void* d_out, int out_size, void* d_ws, size_t ws_size,
                              hipStream_t stream)
{
  const float* h   = (const float*)d_in[0];
  const float* x   = (const float*)d_in[1];
  const int*   ei  = (const int*)d_in[2];
  const float* ew1 = (const float*)d_in[3];
  const float* eb1 = (const float*)d_in[4];
  const float* ew2 = (const float*)d_in[5];
  const float* eb2 = (const float*)d_in[6];
  const float* nw1 = (const float*)d_in[7];
  const float* nb1 = (const float*)d_in[8];
  const float* nw2 = (const float*)d_in[9];
  const float* nb2 = (const float*)d_in[10];
  const float* cw1 = (const float*)d_in[11];
  const float* cb1 = (const float*)d_in[12];
  const float* cw2 = (const float*)d_in[13];

  char* ws = (char*)d_ws;
  float* m_i        = (float*)(ws);                       // 10,240,000 B
  int*   counts     = (int*)  (ws + 10240000);            //     80,000 B
  int*   starts     = (int*)  (ws + 10320000);            //     80,016 B (20001 ints)
  int*   cursor     = (int*)  (ws + 10400016);            //     80,000 B
  int*   edge_order = (int*)  (ws + 10480016);            //  2,560,000 B
  float* xw         = (float*)(ws + 13040016);            // 10,240,000 B
  unsigned short* m_sorted = (unsigned short*)(ws + 23280016); // 163,840,000 B
  constexpr size_t OFF_PK = 187120016;
  unsigned short* ew1pk = (unsigned short*)(ws + OFF_PK);
  unsigned short* ew2pk = (unsigned short*)(ws + OFF_PK + 65536);
  unsigned short* cw1pk = (unsigned short*)(ws + OFF_PK + 98304);
  unsigned short* nw1pk = (unsigned short*)(ws + OFF_PK + 131072);
  unsigned short* nw2pk = (unsigned short*)(ws + OFF_PK + 196608);

  hipMemsetAsync(counts, 0, 80000, stream);

  pack_weights<<<128, 256, 0, stream>>>(ew1, ew1pk, 256 * 128);
  pack_weights<<<64,  256, 0, stream>>>(ew2, ew2pk, 128 * 128);
  pack_weights<<<64,  256, 0, stream>>>(cw1, cw1pk, 128 * 128);
  pack_weights<<<128, 256, 0, stream>>>(nw1, nw1pk, 256 * 128);
  pack_weights<<<64,  256, 0, stream>>>(nw2, nw2pk, 128 * 128);

  hist_kernel<<<(NE + 255) / 256, 256, 0, stream>>>(ei, counts);
  scan_kernel<<<1, 64, 0, stream>>>(counts, starts, cursor);
  scatter_kernel<<<(NE + 255) / 256, 256, 0, stream>>>(ei, cursor, edge_order);

  edge_kernel<<<NE / 64, 256, 0, stream>>>(h, x, ei, edge_order,
                                           ew1pk, ew1, eb1, ew2pk, eb2,
                                           cw1pk, cb1, cw2, m_sorted, xw);

  node_reduce_kernel<<<(NN + 3) / 4, 256, 0, stream>>>(m_sorted, xw, starts, x,
                                                       m_i, (float*)d_out + (size_t)NN * 128);

  node_kernel<<<(NN + 63) / 64, 256, 0, stream>>>(h, m_i, nw1pk, nb1,
                                                  nw2pk, nb2, (float*)d_out);
}

// Round 3
// 444.603 us; speedup vs baseline: 9.9538x; 1.3743x over previous
//
#include <hip/hip_runtime.h>
#include <cstdint>
#include <cstddef>

#define NN 20000
#define NE 640000

typedef __attribute__((ext_vector_type(8))) short short8;
typedef __attribute__((ext_vector_type(4))) float floatx4;

__device__ __forceinline__ unsigned short f2bf(float f) {
  union { float f; unsigned int u; } v; v.f = f;
  return (unsigned short)((v.u + 0x7FFFu + ((v.u >> 16) & 1u)) >> 16);
}
// pack two fp32 -> (bf16(f0) low, bf16(f1) high) with +0x8000 round: 2 adds + 1 v_perm
__device__ __forceinline__ unsigned int pack2bf(float f0, float f1) {
  union { float f; unsigned int u; } a, b; a.f = f0; b.f = f1;
  return __builtin_amdgcn_perm(b.u + 0x8000u, a.u + 0x8000u, 0x07060302u);
}
__device__ __forceinline__ float silu_f(float v) {
  return v / (1.0f + __expf(-v));
}
__device__ __forceinline__ bool idx_is64(const int* ei) {
  return ((ei[1] | ei[3] | ei[5] | ei[7] | ei[9] | ei[11]) == 0);
}

// packed-A LDS layout: element (k, m) of a [64 x K] tile lives at
// ((k/8)*64 + m)*8 + (k%8) shorts -> lane's 8 consecutive k are 16B contiguous.
#define AIDX(k, m) (((((k) >> 3) * 64 + (m)) << 3) + ((k) & 7))

// Wave computes [64 x 32] output slab; lane's two output cols are c0=n0+2*l16, c0+1.
template<int KT>
__device__ __forceinline__ void gemm_tile(const unsigned short* Alds,
                                          const unsigned short* __restrict__ Wpk,
                                          floatx4 acc[4][2],
                                          int quad, int l16, int n0)
{
#pragma unroll
  for (int mt = 0; mt < 4; ++mt) {
    acc[mt][0] = (floatx4)0.0f;
    acc[mt][1] = (floatx4)0.0f;
  }
  const int c0 = n0 + 2 * l16;
#pragma unroll
  for (int kt = 0; kt < KT; ++kt) {
    const int kb = kt * 4 + quad;
    short8 b0 = *(const short8*)&Wpk[(kb * 128 + c0) * 8];
    short8 b1 = *(const short8*)&Wpk[(kb * 128 + c0 + 1) * 8];
#pragma unroll
    for (int mt = 0; mt < 4; ++mt) {
      short8 a = *(const short8*)&Alds[(kb * 64 + mt * 16 + l16) * 8];
      acc[mt][0] = __builtin_amdgcn_mfma_f32_16x16x32_bf16(a, b0, acc[mt][0], 0, 0, 0);
      acc[mt][1] = __builtin_amdgcn_mfma_f32_16x16x32_bf16(a, b1, acc[mt][1], 0, 0, 0);
    }
  }
}

// ---- one kernel packs h (bf16) + all 5 weights (packed-B layout) ----
__device__ __forceinline__ void packw(const float* __restrict__ src,
                                      unsigned short* __restrict__ dst,
                                      int bi, int t) {
  int idx = bi * 256 + t;
  int k = idx >> 7, n = idx & 127;
  dst[(((k >> 3) * 128 + n) << 3) + (k & 7)] = f2bf(src[idx]);
}

__global__ __launch_bounds__(256) void pack_all(
    const float* __restrict__ h,
    const float* __restrict__ ew1, const float* __restrict__ ew2,
    const float* __restrict__ cw1, const float* __restrict__ nw1,
    const float* __restrict__ nw2,
    unsigned short* __restrict__ h_bf,
    unsigned short* __restrict__ ew1pk, unsigned short* __restrict__ ew2pk,
    unsigned short* __restrict__ cw1pk, unsigned short* __restrict__ nw1pk,
    unsigned short* __restrict__ nw2pk)
{
  const int b = blockIdx.x, t = threadIdx.x;
  if (b < 1250) {
    const int idx = (b * 256 + t) * 8;  // 1250*256*8 == NN*128
    float4 v0 = *(const float4*)(h + idx);
    float4 v1 = *(const float4*)(h + idx + 4);
    unsigned int u0 = pack2bf(v0.x, v0.y), u1 = pack2bf(v0.z, v0.w);
    unsigned int u2 = pack2bf(v1.x, v1.y), u3 = pack2bf(v1.z, v1.w);
    uint4 o; o.x = u0; o.y = u1; o.z = u2; o.w = u3;
    *(uint4*)&h_bf[idx] = o;
    return;
  }
  int b2 = b - 1250;
  if (b2 < 128) { packw(ew1, ew1pk, b2, t); return; }  // rows 0..255 only
  b2 -= 128;
  if (b2 < 64)  { packw(ew2, ew2pk, b2, t); return; }
  b2 -= 64;
  if (b2 < 64)  { packw(cw1, cw1pk, b2, t); return; }
  b2 -= 64;
  if (b2 < 128) { packw(nw1, nw1pk, b2, t); return; }
  b2 -= 128;
  packw(nw2, nw2pk, b2, t);
}

// ---- CSR build ----
__global__ void hist_kernel(const int* __restrict__ ei, int* __restrict__ counts) {
  int e = blockIdx.x * blockDim.x + threadIdx.x;
  if (e >= NE) return;
  const bool is64 = idx_is64(ei);
  int r = is64 ? ei[2 * e] : ei[e];
  atomicAdd(&counts[r], 1);
}

__global__ __launch_bounds__(1024) void scan_kernel(
    const int* __restrict__ counts,
    int* __restrict__ starts, int* __restrict__ cursor)
{
  __shared__ int s_wsum[16];
  __shared__ int s_woff[16];
  const int tid = threadIdx.x;
  const int lane = tid & 63, w = tid >> 6;
  const int base = tid * 20;
  int loc[20];
  int tot = 0;
#pragma unroll
  for (int i = 0; i < 20; ++i) {
    const int idx = base + i;
    int v = (idx < NN) ? counts[idx] : 0;
    loc[i] = tot;
    tot += v;
  }
  int s = tot;
#pragma unroll
  for (int d = 1; d < 64; d <<= 1) {
    int t = __shfl_up(s, d);
    if (lane >= d) s += t;
  }
  if (lane == 63) s_wsum[w] = s;
  __syncthreads();
  if (w == 0 && lane < 16) {
    int v = s_wsum[lane];
    int ss = v;
#pragma unroll
    for (int d = 1; d < 16; d <<= 1) {
      int t = __shfl_up(ss, d);
      if (lane >= d) ss += t;
    }
    s_woff[lane] = ss - v;  // exclusive
  }
  __syncthreads();
  const int excl_thread = s_woff[w] + (s - tot);
#pragma unroll
  for (int i = 0; i < 20; ++i) {
    const int idx = base + i;
    if (idx < NN) {
      const int e = excl_thread + loc[i];
      starts[idx] = e;
      cursor[idx] = e;
    }
  }
  if (tid == 0) starts[NN] = NE;
}

__global__ void scatter_kernel(const int* __restrict__ ei,
                               int* __restrict__ cursor,
                               int* __restrict__ edge_order) {
  int e = blockIdx.x * blockDim.x + threadIdx.x;
  if (e >= NE) return;
  const bool is64 = idx_is64(ei);
  int r = is64 ? ei[2 * e] : ei[e];
  int pos = atomicAdd(&cursor[r], 1);
  edge_order[pos] = e;
}

// ---- edge MLP over sorted edges ----
__global__ __launch_bounds__(256) void edge_kernel(
    const unsigned short* __restrict__ h_bf, const float* __restrict__ x,
    const int* __restrict__ ei, const int* __restrict__ edge_order,
    const unsigned short* __restrict__ ew1pk, const float* __restrict__ ew1full,
    const float* __restrict__ eb1,
    const unsigned short* __restrict__ ew2pk, const float* __restrict__ eb2,
    const unsigned short* __restrict__ cw1pk, const float* __restrict__ cb1,
    const float* __restrict__ cw2,
    unsigned short* __restrict__ m_sorted, float* __restrict__ xw)
{
  __shared__ __align__(16) unsigned short A1[16384]; // 32KB; lower 16KB reused as layer2 input
  __shared__ __align__(16) unsigned short A3[8192];  // 16KB: m_ij bf16 (coord-layer A input)
  __shared__ float s_cd[64][3];
  __shared__ float s_rad[64];
  __shared__ float s_cw2[128];
  __shared__ float s_dotp[4][64];

  const int tid  = threadIdx.x;
  const int wave = tid >> 6;
  const int lane = tid & 63;
  const int quad = lane >> 4;
  const int l16  = lane & 15;
  const int blk  = blockIdx.x;
  const int n0   = wave * 32;
  const int c0   = n0 + 2 * l16, c1 = c0 + 1;

  if (tid < 128) s_cw2[tid] = cw2[tid];
  const bool is64 = idx_is64(ei);

  // ---- gather: 4 threads per edge, pure bf16 copies
  {
    const int e = tid >> 2, p = tid & 3;
    const int ge = edge_order[blk * 64 + e];
    int r, c;
    if (is64) { r = ei[2 * ge]; c = ei[2 * (NE + ge)]; }
    else      { r = ei[ge];     c = ei[NE + ge]; }
    if (p == 0) {
      float dx = x[r * 3 + 0] - x[c * 3 + 0];
      float dy = x[r * 3 + 1] - x[c * 3 + 1];
      float dz = x[r * 3 + 2] - x[c * 3 + 2];
      s_cd[e][0] = dx; s_cd[e][1] = dy; s_cd[e][2] = dz;
      s_rad[e] = dx * dx + dy * dy + dz * dz;
    }
    const unsigned short* hr = h_bf + (size_t)r * 128 + p * 32;
    const unsigned short* hc = h_bf + (size_t)c * 128 + p * 32;
#pragma unroll
    for (int i = 0; i < 4; ++i) {
      short8 v = *(const short8*)(hr + i * 8);
      *(short8*)&A1[((p * 4 + i) * 64 + e) * 8] = v;
      short8 u = *(const short8*)(hc + i * 8);
      *(short8*)&A1[((16 + p * 4 + i) * 64 + e) * 8] = u;
    }
  }
  __syncthreads();

  // ---- layer 1: K=256 (+ radial column + bias), silu -> A1 lower half
  floatx4 acc1[4][2];
  gemm_tile<8>(A1, ew1pk, acc1, quad, l16, n0);
  {
    const float b0 = eb1[c0], b1 = eb1[c1];
    const float w0 = ew1full[256 * 128 + c0], w1 = ew1full[256 * 128 + c1];
    __syncthreads();  // all waves done reading A1 before overwrite
#pragma unroll
    for (int mt = 0; mt < 4; ++mt) {
#pragma unroll
      for (int r = 0; r < 4; ++r) {
        const int m = mt * 16 + quad * 4 + r;
        const float rv = s_rad[m];
        const float v0 = silu_f(acc1[mt][0][r] + b0 + rv * w0);
        const float v1 = silu_f(acc1[mt][1][r] + b1 + rv * w1);
        *(unsigned int*)&A1[AIDX(c0, m)] = pack2bf(v0, v1);
      }
    }
  }
  __syncthreads();

  // ---- layer 2: K=128, silu -> m_ij into A3
  floatx4 acc2[4][2];
  gemm_tile<4>(A1, ew2pk, acc2, quad, l16, n0);
  {
    const float b0 = eb2[c0], b1 = eb2[c1];
#pragma unroll
    for (int mt = 0; mt < 4; ++mt) {
#pragma unroll
      for (int r = 0; r < 4; ++r) {
        const int m = mt * 16 + quad * 4 + r;
        const float v0 = silu_f(acc2[mt][0][r] + b0);
        const float v1 = silu_f(acc2[mt][1][r] + b1);
        *(unsigned int*)&A3[AIDX(c0, m)] = pack2bf(v0, v1);
      }
    }
  }
  __syncthreads();

  // ---- coord layer: silu(m_ij @ cw1 + cb1) . cw2, reduced in-register
  floatx4 acc3[4][2];
  gemm_tile<4>(A3, cw1pk, acc3, quad, l16, n0);
  {
    const float b0 = cb1[c0], b1 = cb1[c1];
    const float wa = s_cw2[c0], wb = s_cw2[c1];
#pragma unroll
    for (int mt = 0; mt < 4; ++mt) {
#pragma unroll
      for (int r = 0; r < 4; ++r) {
        float dv = silu_f(acc3[mt][0][r] + b0) * wa +
                   silu_f(acc3[mt][1][r] + b1) * wb;
        dv += __shfl_xor(dv, 1);
        dv += __shfl_xor(dv, 2);
        dv += __shfl_xor(dv, 4);
        dv += __shfl_xor(dv, 8);
        if (l16 == 0) s_dotp[wave][mt * 16 + quad * 4 + r] = dv;
      }
    }
  }
  __syncthreads();

  // ---- store: m_sorted (coalesced 16B/lane) + xw
  {
    const int e = tid >> 2, p = tid & 3;
    const float dot = s_dotp[0][e] + s_dotp[1][e] + s_dotp[2][e] + s_dotp[3][e];
    const size_t sp = (size_t)blk * 64 + e;
    if (p < 3) xw[sp * 4 + p] = s_cd[e][p] * dot;
#pragma unroll
    for (int i = 0; i < 4; ++i) {
      const int kb = p * 4 + i;
      short8 v = *(const short8*)&A3[(kb * 64 + e) * 8];
      *(short8*)&m_sorted[sp * 128 + kb * 8] = v;
    }
  }
}

// ---- per-node segment reduce: m_i (bf16 packed) + final x output ----
__global__ __launch_bounds__(256) void node_reduce_kernel(
    const unsigned short* __restrict__ m_sorted,
    const float* __restrict__ xw,
    const int* __restrict__ starts,
    const float* __restrict__ x,
    unsigned short* __restrict__ m_bf, float* __restrict__ out_x)
{
  union bfu { unsigned int u; struct { unsigned short lo, hi; } s; };
  const int wave = threadIdx.x >> 6, lane = threadIdx.x & 63;
  const int node = blockIdx.x * 4 + wave;
  if (node >= NN) return;
  const int s = starts[node], e = starts[node + 1];
  float a0 = 0.f, a1 = 0.f, b0 = 0.f, b1 = 0.f, xa = 0.f, xb = 0.f;
  int r = s;
  for (; r + 1 < e; r += 2) {
    unsigned int v0 = *(const unsigned int*)(m_sorted + (size_t)r * 128 + lane * 2);
    unsigned int v1 = *(const unsigned int*)(m_sorted + (size_t)(r + 1) * 128 + lane * 2);
    a0 += (float)__builtin_bit_cast(float, (v0 << 16));
    a1 += __builtin_bit_cast(float, (v0 & 0xFFFF0000u));
    b0 += (float)__builtin_bit_cast(float, (v1 << 16));
    b1 += __builtin_bit_cast(float, (v1 & 0xFFFF0000u));
    if (lane < 3) {
      xa += xw[(size_t)r * 4 + lane];
      xb += xw[(size_t)(r + 1) * 4 + lane];
    }
  }
  if (r < e) {
    unsigned int v0 = *(const unsigned int*)(m_sorted + (size_t)r * 128 + lane * 2);
    a0 += (float)__builtin_bit_cast(float, (v0 << 16));
    a1 += __builtin_bit_cast(float, (v0 & 0xFFFF0000u));
    if (lane < 3) xa += xw[(size_t)r * 4 + lane];
  }
  *(unsigned int*)&m_bf[(size_t)node * 128 + lane * 2] = pack2bf(a0 + b0, a1 + b1);
  if (lane < 3)
    out_x[node * 3 + lane] = x[node * 3 + lane] + (xa + xb) * (1.0f / (float)(NN - 1));
}

// ---- node MLP ----
__global__ __launch_bounds__(256) void node_kernel(
    const unsigned short* __restrict__ h_bf, const float* __restrict__ h,
    const unsigned short* __restrict__ m_bf,
    const unsigned short* __restrict__ nw1pk, const float* __restrict__ nb1,
    const unsigned short* __restrict__ nw2pk, const float* __restrict__ nb2,
    float* __restrict__ out_h)
{
  __shared__ __align__(16) unsigned short A1[16384];

  const int tid  = threadIdx.x;
  const int wave = tid >> 6;
  const int lane = tid & 63;
  const int quad = lane >> 4;
  const int l16  = lane & 15;
  const int blk  = blockIdx.x;
  const int n0   = wave * 32;
  const int c0   = n0 + 2 * l16, c1 = c0 + 1;

  {
    const int e = tid >> 2, p = tid & 3;
    const int row = blk * 64 + e;
    const int rc = row < NN ? row : NN - 1;
    const unsigned short* hr = h_bf + (size_t)rc * 128 + p * 32;
    const unsigned short* mr = m_bf + (size_t)rc * 128 + p * 32;
#pragma unroll
    for (int i = 0; i < 4; ++i) {
      short8 v = *(const short8*)(hr + i * 8);
      *(short8*)&A1[((p * 4 + i) * 64 + e) * 8] = v;
      short8 u = *(const short8*)(mr + i * 8);
      *(short8*)&A1[((16 + p * 4 + i) * 64 + e) * 8] = u;
    }
  }
  __syncthreads();

  floatx4 acc1[4][2];
  gemm_tile<8>(A1, nw1pk, acc1, quad, l16, n0);
  {
    const float b0 = nb1[c0], b1 = nb1[c1];
    __syncthreads();
#pragma unroll
    for (int mt = 0; mt < 4; ++mt) {
#pragma unroll
      for (int r = 0; r < 4; ++r) {
        const int m = mt * 16 + quad * 4 + r;
        const float v0 = silu_f(acc1[mt][0][r] + b0);
        const float v1 = silu_f(acc1[mt][1][r] + b1);
        *(unsigned int*)&A1[AIDX(c0, m)] = pack2bf(v0, v1);
      }
    }
  }
  __syncthreads();

  floatx4 acc2[4][2];
  gemm_tile<4>(A1, nw2pk, acc2, quad, l16, n0);
  {
    const float b0 = nb2[c0], b1 = nb2[c1];
#pragma unroll
    for (int mt = 0; mt < 4; ++mt) {
#pragma unroll
      for (int r = 0; r < 4; ++r) {
        const int m = blk * 64 + mt * 16 + quad * 4 + r;
        if (m < NN) {
          const size_t base = (size_t)m * 128;
          float2 o;
          o.x = h[base + c0] + acc2[mt][0][r] + b0;
          o.y = h[base + c1] + acc2[mt][1][r] + b1;
          *(float2*)&out_h[base + c0] = o;
        }
      }
    }
  }
}

extern "C" void kernel_launch(void* const* d_in, const int* in_sizes, int n_in,
                              void* d_out, int out_size, void* d_ws, size_t ws_size,
                              hipStream_t stream)
{
  const float* h   = (const float*)d_in[0];
  const float* x   = (const float*)d_in[1];
  const int*   ei  = (const int*)d_in[2];
  const float* ew1 = (const float*)d_in[3];
  const float* eb1 = (const float*)d_in[4];
  const float* ew2 = (const float*)d_in[5];
  const float* eb2 = (const float*)d_in[6];
  const float* nw1 = (const float*)d_in[7];
  const float* nb1 = (const float*)d_in[8];
  const float* nw2 = (const float*)d_in[9];
  const float* nb2 = (const float*)d_in[10];
  const float* cw1 = (const float*)d_in[11];
  const float* cb1 = (const float*)d_in[12];
  const float* cw2 = (const float*)d_in[13];

  char* ws = (char*)d_ws;
  int*   counts     = (int*)  (ws);                       //     80,000 B
  int*   starts     = (int*)  (ws + 80000);               //     80,016 B
  int*   cursor     = (int*)  (ws + 160016);              //     80,000 B
  int*   edge_order = (int*)  (ws + 240016);              //  2,560,000 B
  float* xw         = (float*)(ws + 2800016);             // 10,240,000 B
  unsigned short* m_sorted = (unsigned short*)(ws + 13040016);  // 163,840,000 B
  unsigned short* m_bf     = (unsigned short*)(ws + 176880016); //  5,120,000 B
  unsigned short* h_bf     = (unsigned short*)(ws + 182000016); //  5,120,000 B
  constexpr size_t OFF_PK = 187120016;
  unsigned short* ew1pk = (unsigned short*)(ws + OFF_PK);
  unsigned short* ew2pk = (unsigned short*)(ws + OFF_PK + 65536);
  unsigned short* cw1pk = (unsigned short*)(ws + OFF_PK + 98304);
  unsigned short* nw1pk = (unsigned short*)(ws + OFF_PK + 131072);
  unsigned short* nw2pk = (unsigned short*)(ws + OFF_PK + 196608);

  hipMemsetAsync(counts, 0, 80000, stream);

  pack_all<<<1250 + 128 + 64 + 64 + 128 + 64, 256, 0, stream>>>(
      h, ew1, ew2, cw1, nw1, nw2, h_bf, ew1pk, ew2pk, cw1pk, nw1pk, nw2pk);

  hist_kernel<<<(NE + 255) / 256, 256, 0, stream>>>(ei, counts);
  scan_kernel<<<1, 1024, 0, stream>>>(counts, starts, cursor);
  scatter_kernel<<<(NE + 255) / 256, 256, 0, stream>>>(ei, cursor, edge_order);

  edge_kernel<<<NE / 64, 256, 0, stream>>>(h_bf, x, ei, edge_order,
                                           ew1pk, ew1, eb1, ew2pk, eb2,
                                           cw1pk, cb1, cw2, m_sorted, xw);

  node_reduce_kernel<<<(NN + 3) / 4, 256, 0, stream>>>(m_sorted, xw, starts, x,
                                                       m_bf, (float*)d_out + (size_t)NN * 128);

  node_kernel<<<(NN + 63) / 64, 256, 0, stream>>>(h_bf, h, m_bf, nw1pk, nb1,
                                                  nw2pk, nb2, (float*)d_out);
}

// Round 4
// 360.675 us; speedup vs baseline: 12.2700x; 1.2327x over previous
//
#include <hip/hip_runtime.h>
#include <cstdint>
#include <cstddef>

#define NN 20000
#define NE 640000

typedef __attribute__((ext_vector_type(8))) short short8;
typedef __attribute__((ext_vector_type(4))) float floatx4;

__device__ __forceinline__ unsigned short f2bf(float f) {
  union { float f; unsigned int u; } v; v.f = f;
  return (unsigned short)((v.u + 0x7FFFu + ((v.u >> 16) & 1u)) >> 16);
}
// pack two fp32 -> (bf16(f0) low, bf16(f1) high): 2 adds + 1 v_perm
__device__ __forceinline__ unsigned int pack2bf(float f0, float f1) {
  union { float f; unsigned int u; } a, b; a.f = f0; b.f = f1;
  return __builtin_amdgcn_perm(b.u + 0x8000u, a.u + 0x8000u, 0x07060302u);
}
// fast silu: 3 VALU + 2 trans ops (no v_div sequence)
__device__ __forceinline__ float silu_f(float v) {
  float e = __builtin_amdgcn_exp2f(v * -1.44269504f);
  return v * __builtin_amdgcn_rcpf(1.0f + e);
}
__device__ __forceinline__ bool idx_is64(const int* ei) {
  return ((ei[1] | ei[3] | ei[5] | ei[7] | ei[9] | ei[11]) == 0);
}

// packed-A LDS layout: element (k, m) of a [64 x K] tile at
// ((k/8)*64 + m)*8 + (k%8) shorts -> lane's 8 consecutive k are 16B contiguous.
#define AIDX(k, m) (((((k) >> 3) * 64 + (m)) << 3) + ((k) & 7))

// Wave computes [64 x 32] slab; lane's two output cols: c0 = n0+2*l16, c0+1.
template<int KT, bool INIT>
__device__ __forceinline__ void gemm_tile(const unsigned short* Alds,
                                          const unsigned short* __restrict__ Wpk,
                                          floatx4 acc[4][2],
                                          int quad, int l16, int n0)
{
  if (INIT) {
#pragma unroll
    for (int mt = 0; mt < 4; ++mt) {
      acc[mt][0] = (floatx4)0.0f;
      acc[mt][1] = (floatx4)0.0f;
    }
  }
  const int c0 = n0 + 2 * l16;
#pragma unroll
  for (int kt = 0; kt < KT; ++kt) {
    const int kb = kt * 4 + quad;
    short8 b0 = *(const short8*)&Wpk[(kb * 128 + c0) * 8];
    short8 b1 = *(const short8*)&Wpk[(kb * 128 + c0 + 1) * 8];
#pragma unroll
    for (int mt = 0; mt < 4; ++mt) {
      short8 a = *(const short8*)&Alds[(kb * 64 + mt * 16 + l16) * 8];
      acc[mt][0] = __builtin_amdgcn_mfma_f32_16x16x32_bf16(a, b0, acc[mt][0], 0, 0, 0);
      acc[mt][1] = __builtin_amdgcn_mfma_f32_16x16x32_bf16(a, b1, acc[mt][1], 0, 0, 0);
    }
  }
}

// ---- pack h + all weights + histogram, one kernel ----
__device__ __forceinline__ void packw(const float* __restrict__ src,
                                      unsigned short* __restrict__ dst,
                                      int bi, int t) {
  int idx = bi * 256 + t;
  int k = idx >> 7, n = idx & 127;
  dst[(((k >> 3) * 128 + n) << 3) + (k & 7)] = f2bf(src[idx]);
}

__global__ __launch_bounds__(256) void pack_all(
    const float* __restrict__ h,
    const float* __restrict__ ew1, const float* __restrict__ ew2,
    const float* __restrict__ cw1, const float* __restrict__ nw1,
    const float* __restrict__ nw2, const int* __restrict__ ei,
    unsigned short* __restrict__ h_bf,
    unsigned short* __restrict__ ew1pk, unsigned short* __restrict__ ew2pk,
    unsigned short* __restrict__ cw1pk, unsigned short* __restrict__ nw1pk,
    unsigned short* __restrict__ nw2pk, int* __restrict__ counts)
{
  const int b = blockIdx.x, t = threadIdx.x;
  if (b < 1250) {
    const int idx = (b * 256 + t) * 8;  // 1250*256*8 == NN*128
    float4 v0 = *(const float4*)(h + idx);
    float4 v1 = *(const float4*)(h + idx + 4);
    uint4 o;
    o.x = pack2bf(v0.x, v0.y); o.y = pack2bf(v0.z, v0.w);
    o.z = pack2bf(v1.x, v1.y); o.w = pack2bf(v1.z, v1.w);
    *(uint4*)&h_bf[idx] = o;
    return;
  }
  int b2 = b - 1250;
  if (b2 < 128) { packw(ew1, ew1pk, b2, t); return; }  // rows 0..255; row 256 read fp32
  b2 -= 128;
  if (b2 < 64)  { packw(ew2, ew2pk, b2, t); return; }
  b2 -= 64;
  if (b2 < 64)  { packw(cw1, cw1pk, b2, t); return; }
  b2 -= 64;
  if (b2 < 128) { packw(nw1, nw1pk, b2, t); return; }
  b2 -= 128;
  if (b2 < 64)  { packw(nw2, nw2pk, b2, t); return; }
  b2 -= 64;
  // histogram: 2500 blocks
  {
    const int e = b2 * 256 + t;
    const bool is64 = idx_is64(ei);
    int r = is64 ? ei[2 * e] : ei[e];
    atomicAdd(&counts[r], 1);
  }
}

__global__ __launch_bounds__(1024) void scan_kernel(
    const int* __restrict__ counts,
    int* __restrict__ starts, int* __restrict__ cursor)
{
  __shared__ int s_wsum[16];
  __shared__ int s_woff[16];
  const int tid = threadIdx.x;
  const int lane = tid & 63, w = tid >> 6;
  const int base = tid * 20;
  int loc[20];
  int tot = 0;
#pragma unroll
  for (int i = 0; i < 20; ++i) {
    const int idx = base + i;
    int v = (idx < NN) ? counts[idx] : 0;
    loc[i] = tot;
    tot += v;
  }
  int s = tot;
#pragma unroll
  for (int d = 1; d < 64; d <<= 1) {
    int t = __shfl_up(s, d);
    if (lane >= d) s += t;
  }
  if (lane == 63) s_wsum[w] = s;
  __syncthreads();
  if (w == 0 && lane < 16) {
    int v = s_wsum[lane];
    int ss = v;
#pragma unroll
    for (int d = 1; d < 16; d <<= 1) {
      int t = __shfl_up(ss, d);
      if (lane >= d) ss += t;
    }
    s_woff[lane] = ss - v;
  }
  __syncthreads();
  const int excl_thread = s_woff[w] + (s - tot);
#pragma unroll
  for (int i = 0; i < 20; ++i) {
    const int idx = base + i;
    if (idx < NN) {
      const int e = excl_thread + loc[i];
      starts[idx] = e;
      cursor[idx] = e;
    }
  }
  if (tid == 0) starts[NN] = NE;
}

__global__ void scatter_kernel(const int* __restrict__ ei,
                               int* __restrict__ cursor,
                               int* __restrict__ edge_order) {
  int e = blockIdx.x * blockDim.x + threadIdx.x;
  if (e >= NE) return;
  const bool is64 = idx_is64(ei);
  int r = is64 ? ei[2 * e] : ei[e];
  int pos = atomicAdd(&cursor[r], 1);
  edge_order[pos] = e;
}

// ---- edge MLP over sorted edges + in-kernel segmented reduction ----
__global__ __launch_bounds__(256, 4) void edge_kernel(
    const unsigned short* __restrict__ h_bf, const float* __restrict__ x,
    const int* __restrict__ ei, const int* __restrict__ edge_order,
    const unsigned short* __restrict__ ew1pk, const float* __restrict__ ew1full,
    const float* __restrict__ eb1,
    const unsigned short* __restrict__ ew2pk, const float* __restrict__ eb2,
    const unsigned short* __restrict__ cw1pk, const float* __restrict__ cb1,
    const float* __restrict__ cw2,
    float* __restrict__ m_i, float* __restrict__ x_acc)
{
  // A1: h[row] staging K=0..127 (8192 shorts) -> layer2 A -> m_ij^T [128][66]
  __shared__ __align__(16) unsigned short A1[8448];
  // A3: h[col] staging K=128..255 -> m_ij packed-A
  __shared__ __align__(16) unsigned short A3[8192];
  __shared__ float s_cd[64][3];
  __shared__ float s_rad[64];
  __shared__ int   s_row[64];
  __shared__ float s_cw2[128];
  __shared__ float s_dotp[4][64];
  __shared__ unsigned int s_bmask[2];

  const int tid  = threadIdx.x;
  const int wave = tid >> 6;
  const int lane = tid & 63;
  const int quad = lane >> 4;
  const int l16  = lane & 15;
  const int blk  = blockIdx.x;
  const int n0   = wave * 32;
  const int c0   = n0 + 2 * l16, c1 = c0 + 1;
  const int e    = tid >> 2, p = tid & 3;

  if (tid < 128) s_cw2[tid] = cw2[tid];
  const bool is64 = idx_is64(ei);

  // ---- gather: both halves at once (A1 = h[row], A3 = h[col])
  int r, c;
  {
    const int ge = edge_order[blk * 64 + e];
    if (is64) { r = ei[2 * ge]; c = ei[2 * (NE + ge)]; }
    else      { r = ei[ge];     c = ei[NE + ge]; }
    if (p == 0) {
      float dx = x[r * 3 + 0] - x[c * 3 + 0];
      float dy = x[r * 3 + 1] - x[c * 3 + 1];
      float dz = x[r * 3 + 2] - x[c * 3 + 2];
      s_cd[e][0] = dx; s_cd[e][1] = dy; s_cd[e][2] = dz;
      s_rad[e] = dx * dx + dy * dy + dz * dz;
      s_row[e] = r;
    }
    const unsigned short* hr = h_bf + (size_t)r * 128 + p * 32;
    const unsigned short* hc = h_bf + (size_t)c * 128 + p * 32;
#pragma unroll
    for (int i = 0; i < 4; ++i) {
      short8 v = *(const short8*)(hr + i * 8);
      *(short8*)&A1[((p * 4 + i) * 64 + e) * 8] = v;
      short8 u = *(const short8*)(hc + i * 8);
      *(short8*)&A3[((p * 4 + i) * 64 + e) * 8] = u;
    }
  }
  __syncthreads();  // S1

  // run-boundary bitmask (wave 0 == edges 0..63); bit e = "edge e ends a run"
  if (wave == 0) {
    bool bflag = (lane == 63) || (s_row[lane] != s_row[lane + 1]);
    unsigned long long mk = __ballot(bflag);
    if (lane == 0) { s_bmask[0] = (unsigned int)mk; s_bmask[1] = (unsigned int)(mk >> 32); }
  }

  // ---- layer 1: K=256 over both staging buffers
  floatx4 acc1[4][2];
  gemm_tile<4, true >(A1, ew1pk,                acc1, quad, l16, n0);
  gemm_tile<4, false>(A3, ew1pk + 16 * 128 * 8, acc1, quad, l16, n0);
  __syncthreads();  // S2 (A1/A3 consumed)

  // epilogue1 (+radial +bias, silu) -> A1 (layer2 A, K=128)
  {
    const float b0 = eb1[c0], b1 = eb1[c1];
    const float w0 = ew1full[256 * 128 + c0], w1 = ew1full[256 * 128 + c1];
#pragma unroll
    for (int mt = 0; mt < 4; ++mt) {
#pragma unroll
      for (int rr = 0; rr < 4; ++rr) {
        const int m = mt * 16 + quad * 4 + rr;
        const float rv = s_rad[m];
        const float v0 = silu_f(acc1[mt][0][rr] + b0 + rv * w0);
        const float v1 = silu_f(acc1[mt][1][rr] + b1 + rv * w1);
        *(unsigned int*)&A1[AIDX(c0, m)] = pack2bf(v0, v1);
      }
    }
  }
  __syncthreads();  // S3

  // ---- layer 2 -> m_ij into A3 (disjoint from A1; no barrier before writes)
  floatx4 acc2[4][2];
  gemm_tile<4, true>(A1, ew2pk, acc2, quad, l16, n0);
  {
    const float b0 = eb2[c0], b1 = eb2[c1];
#pragma unroll
    for (int mt = 0; mt < 4; ++mt) {
#pragma unroll
      for (int rr = 0; rr < 4; ++rr) {
        const int m = mt * 16 + quad * 4 + rr;
        const float v0 = silu_f(acc2[mt][0][rr] + b0);
        const float v1 = silu_f(acc2[mt][1][rr] + b1);
        *(unsigned int*)&A3[AIDX(c0, m)] = pack2bf(v0, v1);
      }
    }
  }
  __syncthreads();  // S4 (A3 complete; all waves past gemm2 so A1 is free)

  // ---- coord layer: silu(m_ij @ cw1 + cb1) . cw2 -> per-edge dot partials
  floatx4 acc3[4][2];
  gemm_tile<4, true>(A3, cw1pk, acc3, quad, l16, n0);
  {
    const float b0 = cb1[c0], b1 = cb1[c1];
    const float wa = s_cw2[c0], wb = s_cw2[c1];
#pragma unroll
    for (int mt = 0; mt < 4; ++mt) {
#pragma unroll
      for (int rr = 0; rr < 4; ++rr) {
        float dv = silu_f(acc3[mt][0][rr] + b0) * wa +
                   silu_f(acc3[mt][1][rr] + b1) * wb;
        dv += __shfl_xor(dv, 1);
        dv += __shfl_xor(dv, 2);
        dv += __shfl_xor(dv, 4);
        dv += __shfl_xor(dv, 8);
        if (l16 == 0) s_dotp[wave][mt * 16 + quad * 4 + rr] = dv;
      }
    }
  }

  // ---- transpose m_ij into A1T[col*66 + edge] (col-major, stride 33 words)
  {
#pragma unroll
    for (int i = 0; i < 4; ++i) {
      const int kb = p * 4 + i;
      short8 v = *(const short8*)&A3[(kb * 64 + e) * 8];
#pragma unroll
      for (int j = 0; j < 8; ++j)
        A1[(kb * 8 + j) * 66 + e] = (unsigned short)v[j];
    }
  }
  __syncthreads();  // S5

  // ---- m_i segmented reduce: thread = (col, half); flush runs via atomics
  {
    const int col = tid & 127, half = tid >> 7;
    const unsigned int mk = __builtin_amdgcn_readfirstlane(s_bmask[half]);
    const int mstart = half * 32;
    float acc = 0.f;
#pragma unroll
    for (int j = 0; j < 16; ++j) {
      const int m = mstart + j * 2;
      const unsigned int wv = *(const unsigned int*)&A1[col * 66 + m];
      acc += __builtin_bit_cast(float, wv << 16);
      if ((mk >> (j * 2)) & 1u) {
        atomicAdd(&m_i[(size_t)s_row[m] * 128 + col], acc); acc = 0.f;
      }
      acc += __builtin_bit_cast(float, wv & 0xFFFF0000u);
      if ((mk >> (j * 2 + 1)) & 1u) {
        atomicAdd(&m_i[(size_t)s_row[m + 1] * 128 + col], acc); acc = 0.f;
      }
    }
    if (!((mk >> 31) & 1u))  // run continues past this half: flush partial
      atomicAdd(&m_i[(size_t)s_row[mstart + 31] * 128 + col], acc);
  }

  // ---- x_update segmented reduce (wave 0; lane = edge)
  if (wave == 0) {
    const float dt = s_dotp[0][lane] + s_dotp[1][lane] +
                     s_dotp[2][lane] + s_dotp[3][lane];
    float v0 = s_cd[lane][0] * dt, v1 = s_cd[lane][1] * dt, v2 = s_cd[lane][2] * dt;
    const int rowv = s_row[lane];
#pragma unroll
    for (int d = 1; d < 64; d <<= 1) {
      const int idx = lane + d, im = idx & 63;
      const int  rd = __shfl(rowv, im);
      const float u0 = __shfl(v0, im), u1 = __shfl(v1, im), u2 = __shfl(v2, im);
      if (idx < 64 && rd == rowv) { v0 += u0; v1 += u1; v2 += u2; }
    }
    const bool head = (lane == 0) || (s_row[lane - 1] != rowv);
    if (head) {
      atomicAdd(&x_acc[rowv * 3 + 0], v0);
      atomicAdd(&x_acc[rowv * 3 + 1], v1);
      atomicAdd(&x_acc[rowv * 3 + 2], v2);
    }
  }
}

// ---- node MLP (+ fused x finalize) ----
__global__ __launch_bounds__(256) void node_kernel(
    const unsigned short* __restrict__ h_bf, const float* __restrict__ h,
    const float* __restrict__ m_i, const float* __restrict__ x,
    const float* __restrict__ x_acc,
    const unsigned short* __restrict__ nw1pk, const float* __restrict__ nb1,
    const unsigned short* __restrict__ nw2pk, const float* __restrict__ nb2,
    float* __restrict__ out_h, float* __restrict__ out_x)
{
  __shared__ __align__(16) unsigned short A1[16384];

  const int tid  = threadIdx.x;
  const int wave = tid >> 6;
  const int lane = tid & 63;
  const int quad = lane >> 4;
  const int l16  = lane & 15;
  const int blk  = blockIdx.x;
  const int n0   = wave * 32;
  const int c0   = n0 + 2 * l16, c1 = c0 + 1;

  // fused x finalize: 313 blocks x 192 threads cover 60000 elements
  {
    const int g = blk * 192 + tid;
    if (tid < 192 && g < NN * 3)
      out_x[g] = x[g] + x_acc[g] * (1.0f / (float)(NN - 1));
  }

  {
    const int e = tid >> 2, p = tid & 3;
    const int row = blk * 64 + e;
    const int rc = row < NN ? row : NN - 1;
    const unsigned short* hr = h_bf + (size_t)rc * 128 + p * 32;
    const float* mr = m_i + (size_t)rc * 128 + p * 32;
#pragma unroll
    for (int i = 0; i < 4; ++i) {
      short8 v = *(const short8*)(hr + i * 8);
      *(short8*)&A1[((p * 4 + i) * 64 + e) * 8] = v;
      float4 a = *(const float4*)(mr + i * 8);
      float4 b = *(const float4*)(mr + i * 8 + 4);
      uint4 o;
      o.x = pack2bf(a.x, a.y); o.y = pack2bf(a.z, a.w);
      o.z = pack2bf(b.x, b.y); o.w = pack2bf(b.z, b.w);
      *(uint4*)&A1[((16 + p * 4 + i) * 64 + e) * 8] = o;
    }
  }
  __syncthreads();

  floatx4 acc1[4][2];
  gemm_tile<8, true>(A1, nw1pk, acc1, quad, l16, n0);
  {
    const float b0 = nb1[c0], b1 = nb1[c1];
    __syncthreads();
#pragma unroll
    for (int mt = 0; mt < 4; ++mt) {
#pragma unroll
      for (int rr = 0; rr < 4; ++rr) {
        const int m = mt * 16 + quad * 4 + rr;
        const float v0 = silu_f(acc1[mt][0][rr] + b0);
        const float v1 = silu_f(acc1[mt][1][rr] + b1);
        *(unsigned int*)&A1[AIDX(c0, m)] = pack2bf(v0, v1);
      }
    }
  }
  __syncthreads();

  floatx4 acc2[4][2];
  gemm_tile<4, true>(A1, nw2pk, acc2, quad, l16, n0);
  {
    const float b0 = nb2[c0], b1 = nb2[c1];
#pragma unroll
    for (int mt = 0; mt < 4; ++mt) {
#pragma unroll
      for (int rr = 0; rr < 4; ++rr) {
        const int m = blk * 64 + mt * 16 + quad * 4 + rr;
        if (m < NN) {
          const size_t base = (size_t)m * 128;
          float2 o;
          o.x = h[base + c0] + acc2[mt][0][rr] + b0;
          o.y = h[base + c1] + acc2[mt][1][rr] + b1;
          *(float2*)&out_h[base + c0] = o;
        }
      }
    }
  }
}

extern "C" void kernel_launch(void* const* d_in, const int* in_sizes, int n_in,
                              void* d_out, int out_size, void* d_ws, size_t ws_size,
                              hipStream_t stream)
{
  const float* h   = (const float*)d_in[0];
  const float* x   = (const float*)d_in[1];
  const int*   ei  = (const int*)d_in[2];
  const float* ew1 = (const float*)d_in[3];
  const float* eb1 = (const float*)d_in[4];
  const float* ew2 = (const float*)d_in[5];
  const float* eb2 = (const float*)d_in[6];
  const float* nw1 = (const float*)d_in[7];
  const float* nb1 = (const float*)d_in[8];
  const float* nw2 = (const float*)d_in[9];
  const float* nb2 = (const float*)d_in[10];
  const float* cw1 = (const float*)d_in[11];
  const float* cb1 = (const float*)d_in[12];
  const float* cw2 = (const float*)d_in[13];

  char* ws = (char*)d_ws;
  // zeroed region: [counts | x_acc | m_i] = 80000 + 240000 + 10240000
  int*   counts = (int*)  (ws);
  float* x_acc  = (float*)(ws + 80000);
  float* m_i    = (float*)(ws + 320000);
  int*   starts     = (int*)(ws + 10560000);   //     80,016 B
  int*   cursor     = (int*)(ws + 10640016);   //     80,000 B
  int*   edge_order = (int*)(ws + 10720016);   //  2,560,000 B
  unsigned short* h_bf = (unsigned short*)(ws + 13280016);  // 5,120,000 B
  constexpr size_t OFF_PK = 18400016;
  unsigned short* ew1pk = (unsigned short*)(ws + OFF_PK);
  unsigned short* ew2pk = (unsigned short*)(ws + OFF_PK + 65536);
  unsigned short* cw1pk = (unsigned short*)(ws + OFF_PK + 98304);
  unsigned short* nw1pk = (unsigned short*)(ws + OFF_PK + 131072);
  unsigned short* nw2pk = (unsigned short*)(ws + OFF_PK + 196608);

  hipMemsetAsync(ws, 0, 10560000, stream);

  pack_all<<<1250 + 448 + 2500, 256, 0, stream>>>(
      h, ew1, ew2, cw1, nw1, nw2, ei,
      h_bf, ew1pk, ew2pk, cw1pk, nw1pk, nw2pk, counts);

  scan_kernel<<<1, 1024, 0, stream>>>(counts, starts, cursor);
  scatter_kernel<<<(NE + 255) / 256, 256, 0, stream>>>(ei, cursor, edge_order);

  edge_kernel<<<NE / 64, 256, 0, stream>>>(h_bf, x, ei, edge_order,
                                           ew1pk, ew1, eb1, ew2pk, eb2,
                                           cw1pk, cb1, cw2, m_i, x_acc);

  node_kernel<<<(NN + 63) / 64, 256, 0, stream>>>(
      h_bf, h, m_i, x, x_acc, nw1pk, nb1, nw2pk, nb2,
      (float*)d_out, (float*)d_out + (size_t)NN * 128);
}

// Round 5
// 334.450 us; speedup vs baseline: 13.2321x; 1.0784x over previous
//
#include <hip/hip_runtime.h>
#include <cstdint>
#include <cstddef>

#define NN 20000
#define NE 640000

typedef __attribute__((ext_vector_type(8))) short short8;
typedef __attribute__((ext_vector_type(4))) float floatx4;

__device__ __forceinline__ unsigned short f2bf(float f) {
  union { float f; unsigned int u; } v; v.f = f;
  return (unsigned short)((v.u + 0x7FFFu + ((v.u >> 16) & 1u)) >> 16);
}
// pack two fp32 -> (bf16(f0) low, bf16(f1) high): 2 adds + 1 v_perm
__device__ __forceinline__ unsigned int pack2bf(float f0, float f1) {
  union { float f; unsigned int u; } a, b; a.f = f0; b.f = f1;
  return __builtin_amdgcn_perm(b.u + 0x8000u, a.u + 0x8000u, 0x07060302u);
}
// fast silu: no v_div sequence
__device__ __forceinline__ float silu_f(float v) {
  float e = __builtin_amdgcn_exp2f(v * -1.44269504f);
  return v * __builtin_amdgcn_rcpf(1.0f + e);
}
__device__ __forceinline__ bool idx_is64(const int* ei) {
  return ((ei[1] | ei[3] | ei[5] | ei[7] | ei[9] | ei[11]) == 0);
}

// swizzled packed-A LDS layout: element (k, m) of [64 x K] tile at
// ((k/8)*64 + (m ^ ((k/8)&3)))*8 + k%8 shorts. The XOR spreads epilogue
// writes over 16 banks; in the GEMM read path it folds to l16^quad (free).
#define AIDX(k, m) (((((k) >> 3) * 64 + ((m) ^ (((k) >> 3) & 3))) << 3) + ((k) & 7))

// Wave computes [64 x 32] slab; lane's two output cols: c0 = n0+2*l16, c0+1.
template<int KT, bool INIT>
__device__ __forceinline__ void gemm_tile(const unsigned short* Alds,
                                          const unsigned short* __restrict__ Wpk,
                                          floatx4 acc[4][2],
                                          int quad, int l16, int n0)
{
  if (INIT) {
#pragma unroll
    for (int mt = 0; mt < 4; ++mt) {
      acc[mt][0] = (floatx4)0.0f;
      acc[mt][1] = (floatx4)0.0f;
    }
  }
  const int c0 = n0 + 2 * l16;
  const int lsw = l16 ^ quad;  // swizzle folds to a lane constant (kb&3 == quad)
#pragma unroll
  for (int kt = 0; kt < KT; ++kt) {
    const int kb = kt * 4 + quad;
    short8 b0 = *(const short8*)&Wpk[(kb * 128 + c0) * 8];
    short8 b1 = *(const short8*)&Wpk[(kb * 128 + c0 + 1) * 8];
#pragma unroll
    for (int mt = 0; mt < 4; ++mt) {
      short8 a = *(const short8*)&Alds[(kb * 64 + mt * 16 + lsw) * 8];
      acc[mt][0] = __builtin_amdgcn_mfma_f32_16x16x32_bf16(a, b0, acc[mt][0], 0, 0, 0);
      acc[mt][1] = __builtin_amdgcn_mfma_f32_16x16x32_bf16(a, b1, acc[mt][1], 0, 0, 0);
    }
  }
}

// ---- pack h + all weights + histogram, one kernel ----
__device__ __forceinline__ void packw(const float* __restrict__ src,
                                      unsigned short* __restrict__ dst,
                                      int bi, int t) {
  int idx = bi * 256 + t;
  int k = idx >> 7, n = idx & 127;
  dst[(((k >> 3) * 128 + n) << 3) + (k & 7)] = f2bf(src[idx]);
}

__global__ __launch_bounds__(256) void pack_all(
    const float* __restrict__ h,
    const float* __restrict__ ew1, const float* __restrict__ ew2,
    const float* __restrict__ cw1, const float* __restrict__ nw1,
    const float* __restrict__ nw2, const int* __restrict__ ei,
    unsigned short* __restrict__ h_bf,
    unsigned short* __restrict__ ew1pk, unsigned short* __restrict__ ew2pk,
    unsigned short* __restrict__ cw1pk, unsigned short* __restrict__ nw1pk,
    unsigned short* __restrict__ nw2pk, int* __restrict__ counts)
{
  const int b = blockIdx.x, t = threadIdx.x;
  if (b < 1250) {
    const int idx = (b * 256 + t) * 8;  // 1250*256*8 == NN*128
    float4 v0 = *(const float4*)(h + idx);
    float4 v1 = *(const float4*)(h + idx + 4);
    uint4 o;
    o.x = pack2bf(v0.x, v0.y); o.y = pack2bf(v0.z, v0.w);
    o.z = pack2bf(v1.x, v1.y); o.w = pack2bf(v1.z, v1.w);
    *(uint4*)&h_bf[idx] = o;
    return;
  }
  int b2 = b - 1250;
  if (b2 < 128) { packw(ew1, ew1pk, b2, t); return; }  // rows 0..255; row 256 read fp32
  b2 -= 128;
  if (b2 < 64)  { packw(ew2, ew2pk, b2, t); return; }
  b2 -= 64;
  if (b2 < 64)  { packw(cw1, cw1pk, b2, t); return; }
  b2 -= 64;
  if (b2 < 128) { packw(nw1, nw1pk, b2, t); return; }
  b2 -= 128;
  if (b2 < 64)  { packw(nw2, nw2pk, b2, t); return; }
  b2 -= 64;
  // histogram: 2500 blocks
  {
    const int e = b2 * 256 + t;
    const bool is64 = idx_is64(ei);
    int r = is64 ? ei[2 * e] : ei[e];
    atomicAdd(&counts[r], 1);
  }
}

__global__ __launch_bounds__(1024) void scan_kernel(
    const int* __restrict__ counts,
    int* __restrict__ starts, int* __restrict__ cursor)
{
  __shared__ int s_wsum[16];
  __shared__ int s_woff[16];
  const int tid = threadIdx.x;
  const int lane = tid & 63, w = tid >> 6;
  const int base = tid * 20;
  int loc[20];
  int tot = 0;
#pragma unroll
  for (int i = 0; i < 20; ++i) {
    const int idx = base + i;
    int v = (idx < NN) ? counts[idx] : 0;
    loc[i] = tot;
    tot += v;
  }
  int s = tot;
#pragma unroll
  for (int d = 1; d < 64; d <<= 1) {
    int t = __shfl_up(s, d);
    if (lane >= d) s += t;
  }
  if (lane == 63) s_wsum[w] = s;
  __syncthreads();
  if (w == 0 && lane < 16) {
    int v = s_wsum[lane];
    int ss = v;
#pragma unroll
    for (int d = 1; d < 16; d <<= 1) {
      int t = __shfl_up(ss, d);
      if (lane >= d) ss += t;
    }
    s_woff[lane] = ss - v;
  }
  __syncthreads();
  const int excl_thread = s_woff[w] + (s - tot);
#pragma unroll
  for (int i = 0; i < 20; ++i) {
    const int idx = base + i;
    if (idx < NN) {
      const int e = excl_thread + loc[i];
      starts[idx] = e;
      cursor[idx] = e;
    }
  }
  if (tid == 0) starts[NN] = NE;
}

// scatter sorted (row,col) pairs so edge_kernel has zero indirection
__global__ void scatter_kernel(const int* __restrict__ ei,
                               int* __restrict__ cursor,
                               int2* __restrict__ sorted_rc) {
  int e = blockIdx.x * blockDim.x + threadIdx.x;
  if (e >= NE) return;
  const bool is64 = idx_is64(ei);
  int r, c;
  if (is64) { r = ei[2 * e]; c = ei[2 * (NE + e)]; }
  else      { r = ei[e];     c = ei[NE + e]; }
  int pos = atomicAdd(&cursor[r], 1);
  sorted_rc[pos] = make_int2(r, c);
}

// ---- edge MLP over sorted edges + register-level segmented reduction ----
__global__ __launch_bounds__(256, 4) void edge_kernel(
    const unsigned short* __restrict__ h_bf, const float* __restrict__ x,
    const int2* __restrict__ sorted_rc,
    const unsigned short* __restrict__ ew1pk, const float* __restrict__ ew1full,
    const float* __restrict__ eb1,
    const unsigned short* __restrict__ ew2pk, const float* __restrict__ eb2,
    const unsigned short* __restrict__ cw1pk, const float* __restrict__ cb1,
    const float* __restrict__ cw2,
    float* __restrict__ m_i, float* __restrict__ x_acc)
{
  // A1: h[row] K=0..127 staging -> layer2 A -> (s_tail | s_pd) scratch
  __shared__ __align__(16) unsigned short A1[8192];
  // A3: h[col] K=128..255 staging -> m_ij packed-A
  __shared__ __align__(16) unsigned short A3[8192];
  __shared__ float s_cd[64][3];
  __shared__ float s_rad[64];
  __shared__ int   s_row[64];
  __shared__ float s_cw2[128];
  __shared__ unsigned int s_bmask[2];

  float* s_tailf = (float*)A1;            // [16 chunks][stride 130] = 8320 B
  float* s_pdf   = (float*)&A1[4160];     // [64 edges][stride 21]   = 5376 B

  const int tid  = threadIdx.x;
  const int wave = tid >> 6;
  const int lane = tid & 63;
  const int quad = lane >> 4;
  const int l16  = lane & 15;
  const int blk  = blockIdx.x;
  const int n0   = wave * 32;
  const int c0   = n0 + 2 * l16, c1 = c0 + 1;
  const int e    = tid >> 2, p = tid & 3;

  if (tid < 128) s_cw2[tid] = cw2[tid];

  // ---- gather: A1 = h[row], A3 = h[col], swizzled rows (e ^ i)
  {
    const int2 rc = sorted_rc[blk * 64 + e];
    const int r = rc.x, c = rc.y;
    if (p == 0) {
      float dx = x[r * 3 + 0] - x[c * 3 + 0];
      float dy = x[r * 3 + 1] - x[c * 3 + 1];
      float dz = x[r * 3 + 2] - x[c * 3 + 2];
      s_cd[e][0] = dx; s_cd[e][1] = dy; s_cd[e][2] = dz;
      s_rad[e] = dx * dx + dy * dy + dz * dz;
      s_row[e] = r;
    }
    const unsigned short* hr = h_bf + (size_t)r * 128 + p * 32;
    const unsigned short* hc = h_bf + (size_t)c * 128 + p * 32;
#pragma unroll
    for (int i = 0; i < 4; ++i) {
      short8 v = *(const short8*)(hr + i * 8);
      *(short8*)&A1[((p * 4 + i) * 64 + (e ^ i)) * 8] = v;
      short8 u = *(const short8*)(hc + i * 8);
      *(short8*)&A3[((p * 4 + i) * 64 + (e ^ i)) * 8] = u;
    }
  }
  __syncthreads();  // S1

  // run-boundary bitmask: bit m = "edge m ends a run"
  if (wave == 0) {
    bool bflag = (lane == 63) || (s_row[lane] != s_row[lane + 1]);
    unsigned long long mk = __ballot(bflag);
    if (lane == 0) { s_bmask[0] = (unsigned int)mk; s_bmask[1] = (unsigned int)(mk >> 32); }
  }

  // ---- layer 1: K=256 over both staging buffers
  floatx4 acc1[4][2];
  gemm_tile<4, true >(A1, ew1pk,                acc1, quad, l16, n0);
  gemm_tile<4, false>(A3, ew1pk + 16 * 128 * 8, acc1, quad, l16, n0);
  __syncthreads();  // S2

  // epilogue1 (+radial +bias, silu) -> A1 (layer2 A, K=128)
  {
    const float b0 = eb1[c0], b1 = eb1[c1];
    const float w0 = ew1full[256 * 128 + c0], w1 = ew1full[256 * 128 + c1];
#pragma unroll
    for (int mt = 0; mt < 4; ++mt) {
#pragma unroll
      for (int rr = 0; rr < 4; ++rr) {
        const int m = mt * 16 + quad * 4 + rr;
        const float rv = s_rad[m];
        const float v0 = silu_f(acc1[mt][0][rr] + b0 + rv * w0);
        const float v1 = silu_f(acc1[mt][1][rr] + b1 + rv * w1);
        *(unsigned int*)&A1[AIDX(c0, m)] = pack2bf(v0, v1);
      }
    }
  }
  __syncthreads();  // S3

  // ---- layer 2 -> m_ij into A3; in-lane segmented sums from fp32 registers
  const unsigned long long mk =
      ((unsigned long long)s_bmask[1] << 32) | (unsigned long long)s_bmask[0];
  floatx4 acc2[4][2];
  gemm_tile<4, true>(A1, ew2pk, acc2, quad, l16, n0);
  float t0[4], t1[4];  // per-chunk tails (chunk = 4 consecutive edges)
  {
    const float b0 = eb2[c0], b1 = eb2[c1];
#pragma unroll
    for (int mt = 0; mt < 4; ++mt) {
      float v0[4], v1[4];
      const int mbase = mt * 16 + quad * 4;
#pragma unroll
      for (int rr = 0; rr < 4; ++rr) {
        v0[rr] = silu_f(acc2[mt][0][rr] + b0);
        v1[rr] = silu_f(acc2[mt][1][rr] + b1);
        *(unsigned int*)&A3[AIDX(c0, mbase + rr)] = pack2bf(v0[rr], v1[rr]);
      }
      const unsigned nib = (unsigned)(mk >> mbase) & 0xFu;
      if (nib == 0) {  // fast path: no boundary in this chunk
        t0[mt] = (v0[0] + v0[1]) + (v0[2] + v0[3]);
        t1[mt] = (v1[0] + v1[1]) + (v1[2] + v1[3]);
      } else {
        float a0 = 0.f, a1 = 0.f;
#pragma unroll
        for (int rr = 0; rr < 4; ++rr) {
          a0 += v0[rr]; a1 += v1[rr];
          if ((nib >> rr) & 1u) {
            const int rw = s_row[mbase + rr];
            atomicAdd(&m_i[(size_t)rw * 128 + c0], a0);
            atomicAdd(&m_i[(size_t)rw * 128 + c1], a1);
            a0 = 0.f; a1 = 0.f;
          }
        }
        t0[mt] = a0; t1[mt] = a1;
      }
    }
  }
  __syncthreads();  // S4 (A3 complete; A1 free for scratch)

  // ---- coord layer: silu(m_ij @ cw1 + cb1) . cw2 -> per-lane dot partials
  floatx4 acc3[4][2];
  gemm_tile<4, true>(A3, cw1pk, acc3, quad, l16, n0);
  {
    const float b0 = cb1[c0], b1 = cb1[c1];
    const float wa = s_cw2[c0], wb = s_cw2[c1];
#pragma unroll
    for (int mt = 0; mt < 4; ++mt) {
#pragma unroll
      for (int rr = 0; rr < 4; ++rr) {
        const int m = mt * 16 + quad * 4 + rr;
        s_pdf[m * 21 + l16] = silu_f(acc3[mt][0][rr] + b0) * wa +
                              silu_f(acc3[mt][1][rr] + b1) * wb;
      }
    }
  }
  // chunk tails -> s_tail[ci][col] (float2, stride 130)
#pragma unroll
  for (int mt = 0; mt < 4; ++mt) {
    const int ci = mt * 4 + quad;
    float2 tv; tv.x = t0[mt]; tv.y = t1[mt];
    *(float2*)&s_tailf[ci * 130 + c0] = tv;
  }
  __syncthreads();  // S5

  // ---- carry walk: merge chunk tails along the sorted edge order
  {
    const int col = tid & 127, hf = tid >> 7;
    float carry = 0.f;
#pragma unroll
    for (int i = 0; i < 8; ++i) {
      const int ci = hf * 8 + i;
      const unsigned nib2 = (unsigned)(mk >> (4 * ci)) & 0xFu;  // uniform
      const float tv = s_tailf[ci * 130 + col];
      if (nib2) {
        if (carry != 0.f)
          atomicAdd(&m_i[(size_t)s_row[4 * ci] * 128 + col], carry);
        carry = tv;
      } else {
        carry += tv;
      }
    }
    if (carry != 0.f)
      atomicAdd(&m_i[(size_t)s_row[hf * 32 + 31] * 128 + col], carry);
  }

  // ---- x_update segmented reduce (wave 0; lane = edge)
  if (wave == 0) {
    float dt = 0.f;
#pragma unroll
    for (int i = 0; i < 16; ++i) dt += s_pdf[lane * 21 + i];
    float v0 = s_cd[lane][0] * dt, v1 = s_cd[lane][1] * dt, v2 = s_cd[lane][2] * dt;
    const int rowv = s_row[lane];
#pragma unroll
    for (int d = 1; d < 64; d <<= 1) {
      const int idx = lane + d, im = idx & 63;
      const int  rd = __shfl(rowv, im);
      const float u0 = __shfl(v0, im), u1 = __shfl(v1, im), u2 = __shfl(v2, im);
      if (idx < 64 && rd == rowv) { v0 += u0; v1 += u1; v2 += u2; }
    }
    const bool head = (lane == 0) || (s_row[lane - 1] != rowv);
    if (head) {
      atomicAdd(&x_acc[rowv * 3 + 0], v0);
      atomicAdd(&x_acc[rowv * 3 + 1], v1);
      atomicAdd(&x_acc[rowv * 3 + 2], v2);
    }
  }
}

// ---- node MLP (+ fused x finalize) ----
__global__ __launch_bounds__(256) void node_kernel(
    const unsigned short* __restrict__ h_bf, const float* __restrict__ h,
    const float* __restrict__ m_i, const float* __restrict__ x,
    const float* __restrict__ x_acc,
    const unsigned short* __restrict__ nw1pk, const float* __restrict__ nb1,
    const unsigned short* __restrict__ nw2pk, const float* __restrict__ nb2,
    float* __restrict__ out_h, float* __restrict__ out_x)
{
  __shared__ __align__(16) unsigned short A1[16384];

  const int tid  = threadIdx.x;
  const int wave = tid >> 6;
  const int lane = tid & 63;
  const int quad = lane >> 4;
  const int l16  = lane & 15;
  const int blk  = blockIdx.x;
  const int n0   = wave * 32;
  const int c0   = n0 + 2 * l16, c1 = c0 + 1;

  // fused x finalize: 313 blocks x 192 threads cover 60000 elements
  {
    const int g = blk * 192 + tid;
    if (tid < 192 && g < NN * 3)
      out_x[g] = x[g] + x_acc[g] * (1.0f / (float)(NN - 1));
  }

  {
    const int e = tid >> 2, p = tid & 3;
    const int row = blk * 64 + e;
    const int rc = row < NN ? row : NN - 1;
    const unsigned short* hr = h_bf + (size_t)rc * 128 + p * 32;
    const float* mr = m_i + (size_t)rc * 128 + p * 32;
#pragma unroll
    for (int i = 0; i < 4; ++i) {
      short8 v = *(const short8*)(hr + i * 8);
      *(short8*)&A1[((p * 4 + i) * 64 + (e ^ i)) * 8] = v;
      float4 a = *(const float4*)(mr + i * 8);
      float4 b = *(const float4*)(mr + i * 8 + 4);
      uint4 o;
      o.x = pack2bf(a.x, a.y); o.y = pack2bf(a.z, a.w);
      o.z = pack2bf(b.x, b.y); o.w = pack2bf(b.z, b.w);
      *(uint4*)&A1[((16 + p * 4 + i) * 64 + (e ^ i)) * 8] = o;
    }
  }
  __syncthreads();

  floatx4 acc1[4][2];
  gemm_tile<8, true>(A1, nw1pk, acc1, quad, l16, n0);
  {
    const float b0 = nb1[c0], b1 = nb1[c1];
    __syncthreads();
#pragma unroll
    for (int mt = 0; mt < 4; ++mt) {
#pragma unroll
      for (int rr = 0; rr < 4; ++rr) {
        const int m = mt * 16 + quad * 4 + rr;
        const float v0 = silu_f(acc1[mt][0][rr] + b0);
        const float v1 = silu_f(acc1[mt][1][rr] + b1);
        *(unsigned int*)&A1[AIDX(c0, m)] = pack2bf(v0, v1);
      }
    }
  }
  __syncthreads();

  floatx4 acc2[4][2];
  gemm_tile<4, true>(A1, nw2pk, acc2, quad, l16, n0);
  {
    const float b0 = nb2[c0], b1 = nb2[c1];
#pragma unroll
    for (int mt = 0; mt < 4; ++mt) {
#pragma unroll
      for (int rr = 0; rr < 4; ++rr) {
        const int m = blk * 64 + mt * 16 + quad * 4 + rr;
        if (m < NN) {
          const size_t base = (size_t)m * 128;
          float2 o;
          o.x = h[base + c0] + acc2[mt][0][rr] + b0;
          o.y = h[base + c1] + acc2[mt][1][rr] + b1;
          *(float2*)&out_h[base + c0] = o;
        }
      }
    }
  }
}

extern "C" void kernel_launch(void* const* d_in, const int* in_sizes, int n_in,
                              void* d_out, int out_size, void* d_ws, size_t ws_size,
                              hipStream_t stream)
{
  const float* h   = (const float*)d_in[0];
  const float* x   = (const float*)d_in[1];
  const int*   ei  = (const int*)d_in[2];
  const float* ew1 = (const float*)d_in[3];
  const float* eb1 = (const float*)d_in[4];
  const float* ew2 = (const float*)d_in[5];
  const float* eb2 = (const float*)d_in[6];
  const float* nw1 = (const float*)d_in[7];
  const float* nb1 = (const float*)d_in[8];
  const float* nw2 = (const float*)d_in[9];
  const float* nb2 = (const float*)d_in[10];
  const float* cw1 = (const float*)d_in[11];
  const float* cb1 = (const float*)d_in[12];
  const float* cw2 = (const float*)d_in[13];

  char* ws = (char*)d_ws;
  // zeroed region: [counts | x_acc | m_i] = 80000 + 240000 + 10240000
  int*   counts = (int*)  (ws);
  float* x_acc  = (float*)(ws + 80000);
  float* m_i    = (float*)(ws + 320000);
  int*   starts = (int*)  (ws + 10560000);   //     80,016 B
  int*   cursor = (int*)  (ws + 10640016);   //     80,000 B
  int2*  sorted_rc = (int2*)(ws + 10720016); //  5,120,000 B
  unsigned short* h_bf = (unsigned short*)(ws + 15840016);  // 5,120,000 B
  constexpr size_t OFF_PK = 20960016;
  unsigned short* ew1pk = (unsigned short*)(ws + OFF_PK);
  unsigned short* ew2pk = (unsigned short*)(ws + OFF_PK + 65536);
  unsigned short* cw1pk = (unsigned short*)(ws + OFF_PK + 98304);
  unsigned short* nw1pk = (unsigned short*)(ws + OFF_PK + 131072);
  unsigned short* nw2pk = (unsigned short*)(ws + OFF_PK + 196608);

  hipMemsetAsync(ws, 0, 10560000, stream);

  pack_all<<<1250 + 448 + 2500, 256, 0, stream>>>(
      h, ew1, ew2, cw1, nw1, nw2, ei,
      h_bf, ew1pk, ew2pk, cw1pk, nw1pk, nw2pk, counts);

  scan_kernel<<<1, 1024, 0, stream>>>(counts, starts, cursor);
  scatter_kernel<<<(NE + 255) / 256, 256, 0, stream>>>(ei, cursor, sorted_rc);

  edge_kernel<<<NE / 64, 256, 0, stream>>>(h_bf, x, sorted_rc,
                                           ew1pk, ew1, eb1, ew2pk, eb2,
                                           cw1pk, cb1, cw2, m_i, x_acc);

  node_kernel<<<(NN + 63) / 64, 256, 0, stream>>>(
      h_bf, h, m_i, x, x_acc, nw1pk, nb1, nw2pk, nb2,
      (float*)d_out, (float*)d_out + (size_t)NN * 128);
}